// Round 5
// baseline (1068.096 us; speedup 1.0000x reference)
//
#include <hip/hip_runtime.h>

// NNPredictor: edge MLP with BN folded into weights.
// R14 = R13 + LDS bank-conflict fixes (k_L12 had 9.6M conflict cycles):
//   - t2 (GEMM2 A-tile) swizzle: pos = plane*512 + ((row&~7)|((row+(row>>3)
//     +plane)&7))*8 on BOTH write and read -> 8-way conflict eliminated.
//     Offsets precomputed per thread (loop-invariant, static-indexed).
//   - tile1 stride 268 -> 269 (odd): combine-phase b128 reads drop from
//     8-way to ~4-way in both k_L12 and k_stats1.
//   - k_ecvt grid 512->1024, k_hstats 200->400 (latency hiding, grid-stride).

#define N_EDGES 800000
#define N_NODES 50000

typedef __attribute__((ext_vector_type(8))) short bf8_t;
typedef __attribute__((ext_vector_type(4))) float f4_t;
typedef __attribute__((ext_vector_type(2))) unsigned int u2_t;
typedef __attribute__((ext_vector_type(4))) unsigned int u4_t;

__device__ __forceinline__ unsigned short f2bf(float f) {
    unsigned int u = __builtin_bit_cast(unsigned int, f);
    u += 0x7FFFu + ((u >> 16) & 1u);
    return (unsigned short)(u >> 16);
}
__device__ __forceinline__ float bf2f(unsigned short s) {
    unsigned int u = ((unsigned int)s) << 16;
    return __builtin_bit_cast(float, u);
}
__device__ __forceinline__ bf8_t cvt8(f4_t x, f4_t y) {
    bf8_t r;
    r[0] = (short)f2bf(x[0]); r[1] = (short)f2bf(x[1]);
    r[2] = (short)f2bf(x[2]); r[3] = (short)f2bf(x[3]);
    r[4] = (short)f2bf(y[0]); r[5] = (short)f2bf(y[1]);
    r[6] = (short)f2bf(y[2]); r[7] = (short)f2bf(y[3]);
    return r;
}

__global__ __launch_bounds__(256) void k_hist(const int* __restrict__ src, const int* __restrict__ dst,
                                              int* __restrict__ cs, int* __restrict__ cd) {
    int i = blockIdx.x * 256 + threadIdx.x;
    if (i < N_EDGES) {
        atomicAdd(&cs[src[i]], 1);
        atomicAdd(&cd[dst[i]], 1);
    }
}

// e -> bf16 in A-tiled layout [blk16][ks(2)][(row*4+colgrp)][8], fused BN0 e-col stats.
__global__ __launch_bounds__(256) void k_ecvt(const float* __restrict__ e,
        unsigned short* __restrict__ ebf, float* __restrict__ sum, float* __restrict__ sq) {
    const int tid = threadIdx.x;
    const int lane = tid & 63;
    const int cg = tid & 7, rr = tid >> 3;
    f4_t sa = {0.f,0.f,0.f,0.f}, sb = sa, qa = sa, qb = sa;
    for (int r = blockIdx.x * 32 + rr; r < N_EDGES; r += gridDim.x * 32) {
        f4_t va = __builtin_nontemporal_load((const f4_t*)(e + (size_t)r * 64 + cg * 8));
        f4_t vb = __builtin_nontemporal_load((const f4_t*)(e + (size_t)r * 64 + cg * 8 + 4));
        sa += va; qa += va * va; sb += vb; qb += vb * vb;
        bf8_t o = cvt8(va, vb);
        __builtin_nontemporal_store(o,
            (bf8_t*)(ebf + (size_t)(r >> 4) * 1024 + (cg >> 2) * 512 + (((r & 15) << 2) + (cg & 3)) * 8));
    }
#pragma unroll
    for (int d = 8; d <= 32; d <<= 1) {
#pragma unroll
        for (int j = 0; j < 4; ++j) {
            sa[j] += __shfl_xor(sa[j], d); qa[j] += __shfl_xor(qa[j], d);
            sb[j] += __shfl_xor(sb[j], d); qb[j] += __shfl_xor(qb[j], d);
        }
    }
    __shared__ float red[128];
    if (tid < 128) red[tid] = 0.f;
    __syncthreads();
    if (lane < 8) {
#pragma unroll
        for (int j = 0; j < 4; ++j) {
            atomicAdd(&red[lane * 8 + j], sa[j]);
            atomicAdd(&red[lane * 8 + 4 + j], sb[j]);
            atomicAdd(&red[64 + lane * 8 + j], qa[j]);
            atomicAdd(&red[64 + lane * 8 + 4 + j], qb[j]);
        }
    }
    __syncthreads();
    if (tid < 64) atomicAdd(&sum[256 + tid], red[tid]);
    else if (tid < 128) atomicAdd(&sq[256 + tid - 64], red[tid]);
}

__global__ __launch_bounds__(256) void k_hstats(const float* __restrict__ h,
                                                const int* __restrict__ cs, const int* __restrict__ cd,
                                                float* __restrict__ sum, float* __restrict__ sq) {
    const int tid = threadIdx.x;
    const int c = tid & 127, g = tid >> 7;
    float ss = 0.f, qs = 0.f, sd = 0.f, qd = 0.f;
    for (int n = blockIdx.x * 2 + g; n < N_NODES; n += gridDim.x * 2) {
        float v = h[(size_t)n * 128 + c];
        float a = (float)cs[n], b = (float)cd[n];
        ss += a * v; qs += a * v * v;
        sd += b * v; qd += b * v * v;
    }
    __shared__ float red[256];
    red[tid] = ss; __syncthreads();
    if (tid < 128) atomicAdd(&sum[tid], red[tid] + red[tid + 128]);
    __syncthreads();
    red[tid] = qs; __syncthreads();
    if (tid < 128) atomicAdd(&sq[tid], red[tid] + red[tid + 128]);
    __syncthreads();
    red[tid] = sd; __syncthreads();
    if (tid < 128) atomicAdd(&sum[128 + tid], red[tid] + red[tid + 128]);
    __syncthreads();
    red[tid] = qd; __syncthreads();
    if (tid < 128) atomicAdd(&sq[128 + tid], red[tid] + red[tid + 128]);
}

__global__ __launch_bounds__(320) void k_fold0(const float* __restrict__ sum, const float* __restrict__ sq,
        const float* __restrict__ g0, const float* __restrict__ b0,
        float* __restrict__ scale0, float* __restrict__ shift0) {
    int j = threadIdx.x;
    if (j < 320) {
        const float invE = 1.f / (float)N_EDGES;
        float mu = sum[j] * invE;
        float var = sq[j] * invE - mu * mu;
        float sc = g0[j] * rsqrtf(var + 1e-5f);
        scale0[j] = sc;
        shift0[j] = b0[j] - mu * sc;
    }
}

__global__ __launch_bounds__(320) void k_foldW1(const float* __restrict__ W1, const float* __restrict__ b1,
        const float* __restrict__ scale0, const float* __restrict__ shift0,
        unsigned short* __restrict__ W1s, unsigned short* __restrict__ W1d,
        unsigned short* __restrict__ W1e, float* __restrict__ b1p) {
    __shared__ float sc[320], sh[320];
    const int tid = threadIdx.x;
    if (tid < 320) { sc[tid] = scale0[tid]; sh[tid] = shift0[tid]; }
    __syncthreads();
    if (tid < 256) {
        float acc = b1[tid];
        const float* wr = W1 + (size_t)tid * 320;
        for (int j = 0; j < 320; ++j) {
            float wv = wr[j];
            acc += wv * sh[j];
            unsigned short wb = f2bf(wv * sc[j]);
            if (j < 128) W1s[tid * 128 + j] = wb;
            else if (j < 256) W1d[tid * 128 + (j - 128)] = wb;
            else W1e[tid * 64 + (j - 256)] = wb;
        }
        b1p[tid] = acc;
    }
}

// P = h @ W'^T : M=50000 (256/block), N=256, K=128. Row-major bf16 output.
__global__ __launch_bounds__(256) void k_P(const float* __restrict__ h,
        const unsigned short* __restrict__ W1s, const unsigned short* __restrict__ W1d,
        unsigned short* __restrict__ Ps, unsigned short* __restrict__ Pd) {
    __shared__ unsigned short tile[16 * 264];
    const int tid = threadIdx.x;
    const int w = tid >> 6, lane = tid & 63, quad = lane >> 4, l15 = lane & 15;
    const unsigned short* W = blockIdx.y ? W1d : W1s;
    unsigned short* P = blockIdx.y ? Pd : Ps;
    const size_t base = (size_t)blockIdx.x * 256;
    bf8_t bfr[4][4];
#pragma unroll
    for (int j = 0; j < 4; ++j) {
        const unsigned short* wp = W + (size_t)((w * 4 + j) * 16 + l15) * 128 + quad * 8;
#pragma unroll
        for (int ks = 0; ks < 4; ++ks) bfr[j][ks] = *(const bf8_t*)(wp + ks * 32);
    }
    const int erow = tid >> 4, ex = tid & 15;
    for (int mc = 0; mc < 16; ++mc) {
        const size_t row0 = base + mc * 16;
        size_t ar = row0 + l15; if (ar >= N_NODES) ar = N_NODES - 1;
        const float* hp = h + ar * 128 + quad * 8;
        bf8_t af[4];
#pragma unroll
        for (int ks = 0; ks < 4; ++ks)
            af[ks] = cvt8(*(const f4_t*)(hp + ks * 32), *(const f4_t*)(hp + ks * 32 + 4));
#pragma unroll
        for (int j = 0; j < 4; ++j) {
            f4_t t = {0.f, 0.f, 0.f, 0.f};
#pragma unroll
            for (int ks = 0; ks < 4; ++ks)
                t = __builtin_amdgcn_mfma_f32_16x16x32_bf16(af[ks], bfr[j][ks], t, 0, 0, 0);
#pragma unroll
            for (int r = 0; r < 4; ++r)
                tile[(quad * 4 + r) * 264 + (w * 4 + j) * 16 + l15] = f2bf(t[r]);
        }
        __syncthreads();
        const size_t orow = row0 + erow;
        if (orow < N_NODES) {
            u4_t v0 = *(const u4_t*)(tile + erow * 264 + ex * 16);
            u4_t v1 = *(const u4_t*)(tile + erow * 264 + ex * 16 + 8);
            *(u4_t*)(P + orow * 256 + ex * 16) = v0;
            *(u4_t*)(P + orow * 256 + ex * 16 + 8) = v1;
        }
        __syncthreads();
    }
}

// Pass A: BN1 stats only, no stores. Vector-gather + f32 tile1 combine
// (double-buffered, 1 sync/mc); per-column stats in registers; cross-wave
// reduce via LDS scratch overlaid on tile1[0]. tile1 stride 269 (odd) to
// break the 8-way bank conflict on the combine-phase b128 reads.
__global__ __launch_bounds__(256) void k_stats1(const unsigned short* __restrict__ ebf,
        const int* __restrict__ src, const int* __restrict__ dst,
        const unsigned short* __restrict__ Ps, const unsigned short* __restrict__ Pd,
        const unsigned short* __restrict__ W1e, const float* __restrict__ b1p,
        float* __restrict__ slots) {
    __shared__ __align__(16) float tile1[2][16 * 269];
    __shared__ int sIdx[256], dIdx[256];
    const int tid = threadIdx.x;
    const int w = tid >> 6, lane = tid & 63, quad = lane >> 4, l15 = lane & 15;
    const int perm = l15 * 4 + quad;
    const size_t base = (size_t)blockIdx.x * 256;
    const size_t blk16 = (size_t)blockIdx.x * 16;
    sIdx[tid] = src[base + tid];
    dIdx[tid] = dst[base + tid];
    bf8_t bfr1[4][2];
    float bias4[4];
#pragma unroll
    for (int j = 0; j < 4; ++j) {
        const unsigned short* wp = W1e + (size_t)((w * 4 + j) * 16 + l15) * 64 + quad * 8;
        bfr1[j][0] = *(const bf8_t*)(wp);
        bfr1[j][1] = *(const bf8_t*)(wp + 32);
        bias4[j] = b1p[(w * 4 + j) * 16 + l15];
    }
    const int erow = tid >> 4, ex = tid & 15;
    float s[16], q[16];
#pragma unroll
    for (int j = 0; j < 16; ++j) { s[j] = 0.f; q[j] = 0.f; }
    __syncthreads();  // publish sIdx/dIdx
    bf8_t af0, af1;
    u4_t gs0, gs1, gd0, gd1;
    {
        const unsigned short* ap = ebf + blk16 * 1024 + perm * 8;
        af0 = __builtin_nontemporal_load((const bf8_t*)(ap));
        af1 = __builtin_nontemporal_load((const bf8_t*)(ap + 512));
        const size_t sr = (size_t)sIdx[erow] * 256, dr = (size_t)dIdx[erow] * 256;
        gs0 = *(const u4_t*)(Ps + sr + ex * 8);
        gs1 = *(const u4_t*)(Ps + sr + ex * 8 + 128);
        gd0 = *(const u4_t*)(Pd + dr + ex * 8);
        gd1 = *(const u4_t*)(Pd + dr + ex * 8 + 128);
    }
    for (int mc = 0; mc < 16; ++mc) {
        float* t1 = tile1[mc & 1];
#pragma unroll
        for (int j = 0; j < 4; ++j) {
            f4_t t = {bias4[j], bias4[j], bias4[j], bias4[j]};
            t = __builtin_amdgcn_mfma_f32_16x16x32_bf16(af0, bfr1[j][0], t, 0, 0, 0);
            t = __builtin_amdgcn_mfma_f32_16x16x32_bf16(af1, bfr1[j][1], t, 0, 0, 0);
#pragma unroll
            for (int r = 0; r < 4; ++r)
                t1[(quad * 4 + r) * 269 + (w * 4 + j) * 16 + l15] = t[r];
        }
        if (mc < 15) {
            const unsigned short* ap = ebf + (blk16 + mc + 1) * 1024 + perm * 8;
            af0 = __builtin_nontemporal_load((const bf8_t*)(ap));
            af1 = __builtin_nontemporal_load((const bf8_t*)(ap + 512));
        }
        // One sync per mc: t1 writes complete; also orders next iter's write
        // of the other buffer behind this iter's reads of it.
        __syncthreads();
#pragma unroll
        for (int i = 0; i < 2; ++i) {
            const float* tp = t1 + erow * 269 + ex * 8 + 128 * i;
            f4_t tv0 = *(const f4_t*)tp;
            f4_t tv1 = *(const f4_t*)(tp + 4);
            const unsigned short* su = (const unsigned short*)(i ? &gs1 : &gs0);
            const unsigned short* du = (const unsigned short*)(i ? &gd1 : &gd0);
#pragma unroll
            for (int j = 0; j < 4; ++j) {
                float v = fmaxf(tv0[j] + bf2f(su[j]) + bf2f(du[j]), 0.f);
                s[i * 8 + j] += v; q[i * 8 + j] += v * v;
            }
#pragma unroll
            for (int j = 0; j < 4; ++j) {
                float v = fmaxf(tv1[j] + bf2f(su[4 + j]) + bf2f(du[4 + j]), 0.f);
                s[i * 8 + 4 + j] += v; q[i * 8 + 4 + j] += v * v;
            }
        }
        if (mc < 15) {
            const size_t sr = (size_t)sIdx[(mc + 1) * 16 + erow] * 256;
            const size_t dr = (size_t)dIdx[(mc + 1) * 16 + erow] * 256;
            gs0 = *(const u4_t*)(Ps + sr + ex * 8);
            gs1 = *(const u4_t*)(Ps + sr + ex * 8 + 128);
            gd0 = *(const u4_t*)(Pd + dr + ex * 8);
            gd1 = *(const u4_t*)(Pd + dr + ex * 8 + 128);
        }
    }
    // Reduce over this wave's 4 rows (row bits live in lane>>4).
#pragma unroll
    for (int j = 0; j < 16; ++j) {
        s[j] += __shfl_xor(s[j], 16); s[j] += __shfl_xor(s[j], 32);
        q[j] += __shfl_xor(q[j], 16); q[j] += __shfl_xor(q[j], 32);
    }
    // Cross-wave reduce via LDS scratch on tile1[0] (last read of tile1[0]
    // was mc=14, ordered behind mc=15's sync; mc=15 readers touch tile1[1]).
    float* scratch = &tile1[0][0];  // 2048 floats
    if (lane < 16) {
#pragma unroll
        for (int j = 0; j < 16; ++j) {
            scratch[(w * 16 + l15) * 16 + j] = s[j];
            scratch[1024 + (w * 16 + l15) * 16 + j] = q[j];
        }
    }
    __syncthreads();
    {
        const int c = tid;  // column 0..255
        const int idx = (c & 7) + (c >> 7) * 8;
        const int exx = (c >> 3) & 15;
        float S = 0.f, Q = 0.f;
#pragma unroll
        for (int ww = 0; ww < 4; ++ww) {
            S += scratch[(ww * 16 + exx) * 16 + idx];
            Q += scratch[1024 + (ww * 16 + exx) * 16 + idx];
        }
        float* sl = slots + (size_t)(blockIdx.x & 63) * 512;
        atomicAdd(&sl[c], S);
        atomicAdd(&sl[256 + c], Q);
    }
}

__global__ __launch_bounds__(256) void k_fold1(const float* __restrict__ slots,
        const float* __restrict__ g1, const float* __restrict__ b1n,
        const float* __restrict__ W2, const float* __restrict__ b2,
        unsigned short* __restrict__ W2p, float* __restrict__ b2p) {
    __shared__ float sc[256], sh[256];
    const int tid = threadIdx.x;
    float S = 0.f, Q = 0.f;
    for (int s = 0; s < 64; ++s) { S += slots[s * 512 + tid]; Q += slots[s * 512 + 256 + tid]; }
    const float invE = 1.f / (float)N_EDGES;
    float mu = S * invE;
    float var = Q * invE - mu * mu;
    float scl = g1[tid] * rsqrtf(var + 1e-5f);
    sc[tid] = scl; sh[tid] = b1n[tid] - mu * scl;
    __syncthreads();
    if (tid < 128) {
        float acc = b2[tid];
        const float* wr = W2 + (size_t)tid * 256;
        for (int j = 0; j < 256; ++j) {
            float wv = wr[j];
            acc += wv * sh[j];
            W2p[tid * 256 + j] = f2bf(wv * sc[j]);
        }
        b2p[tid] = acc;
    }
}

// Pass B: recompute a1 chunk (GEMM1 -> f32 tile1 -> combine) into A-tiled LDS
// (double-buffered, swizzled tile2), then GEMM2 (W2p in regs) -> a2 + BN2 stats.
// t2 swizzle: pos(plane,row) = plane*512 + ((row&~7)|((row+(row>>3)+plane)&7))*8
// applied identically on write and read; offsets precomputed (loop-invariant).
__global__ __launch_bounds__(256) void k_L12(const unsigned short* __restrict__ ebf,
        const int* __restrict__ src, const int* __restrict__ dst,
        const unsigned short* __restrict__ Ps, const unsigned short* __restrict__ Pd,
        const unsigned short* __restrict__ W1e, const float* __restrict__ b1p,
        const unsigned short* __restrict__ W2p, const float* __restrict__ b2p,
        unsigned short* __restrict__ a2c, float* __restrict__ slots) {
    __shared__ __align__(16) float tile1[16 * 269];
    __shared__ unsigned short tile2[2][4096];
    __shared__ int sIdx[256], dIdx[256];
    const int tid = threadIdx.x;
    const int w = tid >> 6, lane = tid & 63, quad = lane >> 4, l15 = lane & 15;
    const int perm = l15 * 4 + quad;
    const size_t base = (size_t)blockIdx.x * 256;
    const size_t blk16 = (size_t)blockIdx.x * 16;
    sIdx[tid] = src[base + tid];
    dIdx[tid] = dst[base + tid];
    bf8_t bfr1[4][2];
    float bias4[4];
#pragma unroll
    for (int j = 0; j < 4; ++j) {
        const unsigned short* wp = W1e + (size_t)((w * 4 + j) * 16 + l15) * 64 + quad * 8;
        bfr1[j][0] = *(const bf8_t*)(wp);
        bfr1[j][1] = *(const bf8_t*)(wp + 32);
        bias4[j] = b1p[(w * 4 + j) * 16 + l15];
    }
    bf8_t bfr2[2][8];
    float bias2[2];
#pragma unroll
    for (int j = 0; j < 2; ++j) {
        const unsigned short* wp = W2p + (size_t)((w * 2 + j) * 16 + l15) * 256 + quad * 8;
#pragma unroll
        for (int ks = 0; ks < 8; ++ks) bfr2[j][ks] = *(const bf8_t*)(wp + ks * 32);
        bias2[j] = b2p[(w * 2 + j) * 16 + l15];
    }
    const int erow = tid >> 4, ex = tid & 15;
    // Precomputed swizzled t2 offsets (shorts), loop-invariant per thread.
    const int rw = erow * 4 + (ex & 3);
    const int kg0 = (ex >> 2), kg1 = kg0 + 4;
    const int woff0 = kg0 * 512 + (((rw & ~7) | ((rw + (rw >> 3) + kg0) & 7)) << 3);
    const int woff1 = kg1 * 512 + (((rw & ~7) | ((rw + (rw >> 3) + kg1) & 7)) << 3);
    int roff[8];
#pragma unroll
    for (int ks = 0; ks < 8; ++ks)
        roff[ks] = ks * 512 + (((perm & ~7) | ((perm + (perm >> 3) + ks) & 7)) << 3);
    float s0 = 0.f, q0 = 0.f, s1 = 0.f, q1 = 0.f;
    __syncthreads();  // publish sIdx/dIdx
    bf8_t af0, af1;
    u4_t gs0, gs1, gd0, gd1;
    {
        const unsigned short* ap = ebf + blk16 * 1024 + perm * 8;
        af0 = __builtin_nontemporal_load((const bf8_t*)(ap));
        af1 = __builtin_nontemporal_load((const bf8_t*)(ap + 512));
        const size_t sr = (size_t)sIdx[erow] * 256, dr = (size_t)dIdx[erow] * 256;
        gs0 = *(const u4_t*)(Ps + sr + ex * 8);
        gs1 = *(const u4_t*)(Ps + sr + ex * 8 + 128);
        gd0 = *(const u4_t*)(Pd + dr + ex * 8);
        gd1 = *(const u4_t*)(Pd + dr + ex * 8 + 128);
    }
    for (int mc = 0; mc < 16; ++mc) {
        unsigned short* t2 = tile2[mc & 1];
#pragma unroll
        for (int j = 0; j < 4; ++j) {
            f4_t t = {bias4[j], bias4[j], bias4[j], bias4[j]};
            t = __builtin_amdgcn_mfma_f32_16x16x32_bf16(af0, bfr1[j][0], t, 0, 0, 0);
            t = __builtin_amdgcn_mfma_f32_16x16x32_bf16(af1, bfr1[j][1], t, 0, 0, 0);
#pragma unroll
            for (int r = 0; r < 4; ++r)
                tile1[(quad * 4 + r) * 269 + (w * 4 + j) * 16 + l15] = t[r];
        }
        if (mc < 15) {
            const unsigned short* ap = ebf + (blk16 + mc + 1) * 1024 + perm * 8;
            af0 = __builtin_nontemporal_load((const bf8_t*)(ap));
            af1 = __builtin_nontemporal_load((const bf8_t*)(ap + 512));
        }
        __syncthreads();  // tile1 complete (also: prev combine-readers done)
#pragma unroll
        for (int i = 0; i < 2; ++i) {
            const float* tp = tile1 + erow * 269 + ex * 8 + 128 * i;
            f4_t tv0 = *(const f4_t*)tp;
            f4_t tv1 = *(const f4_t*)(tp + 4);
            const unsigned short* su = (const unsigned short*)(i ? &gs1 : &gs0);
            const unsigned short* du = (const unsigned short*)(i ? &gd1 : &gd0);
            unsigned short ov[8];
#pragma unroll
            for (int j = 0; j < 4; ++j) {
                float v = tv0[j] + bf2f(su[j]) + bf2f(du[j]);
                ov[j] = f2bf(fmaxf(v, 0.f));
            }
#pragma unroll
            for (int j = 0; j < 4; ++j) {
                float v = tv1[j] + bf2f(su[4 + j]) + bf2f(du[4 + j]);
                ov[4 + j] = f2bf(fmaxf(v, 0.f));
            }
            *(u4_t*)(&t2[i ? woff1 : woff0]) = *(const u4_t*)ov;
        }
        if (mc < 15) {
            const size_t sr = (size_t)sIdx[(mc + 1) * 16 + erow] * 256;
            const size_t dr = (size_t)dIdx[(mc + 1) * 16 + erow] * 256;
            gs0 = *(const u4_t*)(Ps + sr + ex * 8);
            gs1 = *(const u4_t*)(Ps + sr + ex * 8 + 128);
            gd0 = *(const u4_t*)(Pd + dr + ex * 8);
            gd1 = *(const u4_t*)(Pd + dr + ex * 8 + 128);
        }
        __syncthreads();  // tile2[buf] complete
        f4_t acc0 = {bias2[0], bias2[0], bias2[0], bias2[0]};
        f4_t acc1 = {bias2[1], bias2[1], bias2[1], bias2[1]};
#pragma unroll
        for (int ks = 0; ks < 8; ++ks) {
            bf8_t a = *(const bf8_t*)(&t2[roff[ks]]);
            acc0 = __builtin_amdgcn_mfma_f32_16x16x32_bf16(a, bfr2[0][ks], acc0, 0, 0, 0);
            acc1 = __builtin_amdgcn_mfma_f32_16x16x32_bf16(a, bfr2[1][ks], acc1, 0, 0, 0);
        }
        unsigned short* outp = a2c + (blk16 + mc) * 2048;
        unsigned short pv[4];
#pragma unroll
        for (int r = 0; r < 4; ++r) {
            float v = fmaxf(acc0[r], 0.f);
            pv[r] = f2bf(v); s0 += v; q0 += v * v;
        }
        __builtin_nontemporal_store(*(const u2_t*)pv,
            (u2_t*)(outp + (((w * 2) * 16 + l15) * 4 + quad) * 4));
#pragma unroll
        for (int r = 0; r < 4; ++r) {
            float v = fmaxf(acc1[r], 0.f);
            pv[r] = f2bf(v); s1 += v; q1 += v * v;
        }
        __builtin_nontemporal_store(*(const u2_t*)pv,
            (u2_t*)(outp + (((w * 2 + 1) * 16 + l15) * 4 + quad) * 4));
    }
    s0 += __shfl_xor(s0, 16); s0 += __shfl_xor(s0, 32);
    q0 += __shfl_xor(q0, 16); q0 += __shfl_xor(q0, 32);
    s1 += __shfl_xor(s1, 16); s1 += __shfl_xor(s1, 32);
    q1 += __shfl_xor(q1, 16); q1 += __shfl_xor(q1, 32);
    if (lane < 16) {
        float* sl = slots + (size_t)(blockIdx.x & 63) * 256;
        const int c0 = (w * 2) * 16 + l15;
        atomicAdd(&sl[c0], s0); atomicAdd(&sl[128 + c0], q0);
        atomicAdd(&sl[c0 + 16], s1); atomicAdd(&sl[128 + c0 + 16], q1);
    }
}

__global__ __launch_bounds__(128) void k_fold2(const float* __restrict__ slots,
        const float* __restrict__ g2, const float* __restrict__ b2n,
        const float* __restrict__ W3, const float* __restrict__ b3,
        float* __restrict__ w3p, float* __restrict__ b3p) {
    __shared__ float red[128];
    const int tid = threadIdx.x;
    float S = 0.f, Q = 0.f;
    for (int s = 0; s < 64; ++s) { S += slots[s * 256 + tid]; Q += slots[s * 256 + 128 + tid]; }
    const float invE = 1.f / (float)N_EDGES;
    float mu = S * invE;
    float var = Q * invE - mu * mu;
    float scl = g2[tid] * rsqrtf(var + 1e-5f);
    float shf = b2n[tid] - mu * scl;
    w3p[tid] = W3[tid] * scl;
    red[tid] = W3[tid] * shf;
    __syncthreads();
    for (int st = 64; st > 0; st >>= 1) {
        if (tid < st) red[tid] += red[tid + st];
        __syncthreads();
    }
    if (tid == 0) b3p[0] = b3[0] + red[0];
}

// out = a2 . w3' + b3' from C-layout cells; wave per 16-row block, shuffle reduce.
__global__ __launch_bounds__(256) void k_L3(const unsigned short* __restrict__ a2c,
        const float* __restrict__ w3p, const float* __restrict__ b3p, float* __restrict__ out) {
    __shared__ float wl[128];
    const int tid = threadIdx.x;
    if (tid < 128) wl[tid] = w3p[tid];
    __syncthreads();
    const int w = tid >> 6, lane = tid & 63, q = lane >> 4, c = lane & 15;
    const float bb = b3p[0];
#pragma unroll
    for (int i = 0; i < 4; ++i) {
        const size_t b = (size_t)blockIdx.x * 16 + w * 4 + i;
        const unsigned short* bp = a2c + b * 2048 + c * 16 + q * 4;
        float a0 = 0.f, a1r = 0.f, a2r = 0.f, a3r = 0.f;
#pragma unroll
        for (int jt = 0; jt < 8; ++jt) {
            u2_t v = __builtin_nontemporal_load((const u2_t*)(bp + jt * 256));
            const unsigned short* u = (const unsigned short*)&v;
            const float wv = wl[jt * 16 + c];
            a0 += bf2f(u[0]) * wv; a1r += bf2f(u[1]) * wv;
            a2r += bf2f(u[2]) * wv; a3r += bf2f(u[3]) * wv;
        }
#pragma unroll
        for (int d = 1; d <= 8; d <<= 1) {
            a0 += __shfl_xor(a0, d); a1r += __shfl_xor(a1r, d);
            a2r += __shfl_xor(a2r, d); a3r += __shfl_xor(a3r, d);
        }
        if (c == 0) {
            f4_t o = {a0 + bb, a1r + bb, a2r + bb, a3r + bb};
            *(f4_t*)(out + b * 16 + q * 4) = o;
        }
    }
}

extern "C" void kernel_launch(void* const* d_in, const int* in_sizes, int n_in,
                              void* d_out, int out_size, void* d_ws, size_t ws_size,
                              hipStream_t stream) {
    (void)in_sizes; (void)n_in; (void)out_size; (void)ws_size;
    const float* h   = (const float*)d_in[0];
    const float* e   = (const float*)d_in[1];
    const int*   src = (const int*)d_in[2];
    const int*   dst = (const int*)d_in[3];
    const float* bn0_g = (const float*)d_in[4];
    const float* bn0_b = (const float*)d_in[5];
    const float* W1 = (const float*)d_in[6];
    const float* b1 = (const float*)d_in[7];
    const float* bn1_g = (const float*)d_in[8];
    const float* bn1_b = (const float*)d_in[9];
    const float* W2 = (const float*)d_in[10];
    const float* b2 = (const float*)d_in[11];
    const float* bn2_g = (const float*)d_in[12];
    const float* bn2_b = (const float*)d_in[13];
    const float* W3 = (const float*)d_in[14];
    const float* b3 = (const float*)d_in[15];

    char* ws = (char*)d_ws;
    size_t off = 0;
    auto alloc = [&](size_t bytes) { char* p = ws + off; off += (bytes + 255) & ~(size_t)255; return p; };
    int*   cnt_s = (int*)alloc((size_t)N_NODES * 4);
    int*   cnt_d = (int*)alloc((size_t)N_NODES * 4);
    float* bn0_sum = (float*)alloc(320 * 4);
    float* bn0_sq  = (float*)alloc(320 * 4);
    float* bn1_slots = (float*)alloc(64 * 512 * 4);
    float* bn2_slots = (float*)alloc(64 * 256 * 4);
    const size_t zero_end = off;
    float* scale0 = (float*)alloc(320 * 4);
    float* shift0 = (float*)alloc(320 * 4);
    unsigned short* W1s = (unsigned short*)alloc(256 * 128 * 2);
    unsigned short* W1d = (unsigned short*)alloc(256 * 128 * 2);
    unsigned short* W1e = (unsigned short*)alloc(256 * 64 * 2);
    float* b1p = (float*)alloc(256 * 4);
    unsigned short* W2p = (unsigned short*)alloc(128 * 256 * 2);
    float* b2p = (float*)alloc(128 * 4);
    float* w3p = (float*)alloc(128 * 4);
    float* b3p = (float*)alloc(4);
    unsigned short* Ps = (unsigned short*)alloc((size_t)N_NODES * 256 * 2);
    unsigned short* Pd = (unsigned short*)alloc((size_t)N_NODES * 256 * 2);
    unsigned short* ebf = (unsigned short*)alloc((size_t)(N_EDGES / 16) * 2048); // 102.4 MB
    unsigned short* a2c = (unsigned short*)alloc((size_t)(N_EDGES / 16) * 4096); // 204.8 MB

    hipMemsetAsync(d_ws, 0, zero_end, stream);
    k_hist<<<(N_EDGES + 255) / 256, 256, 0, stream>>>(src, dst, cnt_s, cnt_d);
    k_ecvt<<<1024, 256, 0, stream>>>(e, ebf, bn0_sum, bn0_sq);
    k_hstats<<<400, 256, 0, stream>>>(h, cnt_s, cnt_d, bn0_sum, bn0_sq);
    k_fold0<<<1, 320, 0, stream>>>(bn0_sum, bn0_sq, bn0_g, bn0_b, scale0, shift0);
    k_foldW1<<<1, 320, 0, stream>>>(W1, b1, scale0, shift0, W1s, W1d, W1e, b1p);
    k_P<<<dim3(196, 2), 256, 0, stream>>>(h, W1s, W1d, Ps, Pd);
    k_stats1<<<N_EDGES / 256, 256, 0, stream>>>(ebf, src, dst, Ps, Pd, W1e, b1p, bn1_slots);
    k_fold1<<<1, 256, 0, stream>>>(bn1_slots, bn1_g, bn1_b, W2, b2, W2p, b2p);
    k_L12<<<N_EDGES / 256, 256, 0, stream>>>(ebf, src, dst, Ps, Pd, W1e, b1p, W2p, b2p, a2c, bn2_slots);
    k_fold2<<<1, 128, 0, stream>>>(bn2_slots, bn2_g, bn2_b, W3, b3, w3p, b3p);
    k_L3<<<N_EDGES / 256, 256, 0, stream>>>(a2c, w3p, b3p, (float*)d_out);
}

// Round 6
// 987.209 us; speedup vs baseline: 1.0819x; 1.0819x over previous
//
#include <hip/hip_runtime.h>

// NNPredictor: edge MLP with BN folded into weights.
// R15 = R13 revert (R14's LDS "fixes" regressed: stride 269 broke 16B
// alignment of f4_t LDS reads; bank-conflict counter proved structural,
// unchanged at exactly 9.6M across layouts) + packed bf16 conversion:
//   - v_cvt_pk_bf16_f32 (inline asm, RTNE) replaces manual f2bf in all hot
//     paths: cvt8 (k_ecvt/k_P), k_P tile writes, k_L12 combine + epilogue.
//     VALU was the busiest pipe in k_L12 (38%).
//   - grid bumps kept: k_ecvt 1024 blocks, k_hstats 400 blocks.

#define N_EDGES 800000
#define N_NODES 50000

typedef __attribute__((ext_vector_type(8))) short bf8_t;
typedef __attribute__((ext_vector_type(4))) float f4_t;
typedef __attribute__((ext_vector_type(2))) unsigned int u2_t;
typedef __attribute__((ext_vector_type(4))) unsigned int u4_t;

__device__ __forceinline__ unsigned short f2bf(float f) {
    unsigned int u = __builtin_bit_cast(unsigned int, f);
    u += 0x7FFFu + ((u >> 16) & 1u);
    return (unsigned short)(u >> 16);
}
__device__ __forceinline__ float bf2f(unsigned short s) {
    unsigned int u = ((unsigned int)s) << 16;
    return __builtin_bit_cast(float, u);
}
// Packed f32x2 -> bf16x2 (RTNE), lo in [15:0], hi in [31:16].
__device__ __forceinline__ unsigned int cvt_pk(float lo, float hi) {
    unsigned int r;
    asm("v_cvt_pk_bf16_f32 %0, %1, %2" : "=v"(r) : "v"(lo), "v"(hi));
    return r;
}
__device__ __forceinline__ bf8_t cvt8(f4_t x, f4_t y) {
    union { unsigned int u[4]; bf8_t v; } r;
    r.u[0] = cvt_pk(x[0], x[1]);
    r.u[1] = cvt_pk(x[2], x[3]);
    r.u[2] = cvt_pk(y[0], y[1]);
    r.u[3] = cvt_pk(y[2], y[3]);
    return r.v;
}

__global__ __launch_bounds__(256) void k_hist(const int* __restrict__ src, const int* __restrict__ dst,
                                              int* __restrict__ cs, int* __restrict__ cd) {
    int i = blockIdx.x * 256 + threadIdx.x;
    if (i < N_EDGES) {
        atomicAdd(&cs[src[i]], 1);
        atomicAdd(&cd[dst[i]], 1);
    }
}

// e -> bf16 in A-tiled layout [blk16][ks(2)][(row*4+colgrp)][8], fused BN0 e-col stats.
__global__ __launch_bounds__(256) void k_ecvt(const float* __restrict__ e,
        unsigned short* __restrict__ ebf, float* __restrict__ sum, float* __restrict__ sq) {
    const int tid = threadIdx.x;
    const int lane = tid & 63;
    const int cg = tid & 7, rr = tid >> 3;
    f4_t sa = {0.f,0.f,0.f,0.f}, sb = sa, qa = sa, qb = sa;
    for (int r = blockIdx.x * 32 + rr; r < N_EDGES; r += gridDim.x * 32) {
        f4_t va = __builtin_nontemporal_load((const f4_t*)(e + (size_t)r * 64 + cg * 8));
        f4_t vb = __builtin_nontemporal_load((const f4_t*)(e + (size_t)r * 64 + cg * 8 + 4));
        sa += va; qa += va * va; sb += vb; qb += vb * vb;
        bf8_t o = cvt8(va, vb);
        __builtin_nontemporal_store(o,
            (bf8_t*)(ebf + (size_t)(r >> 4) * 1024 + (cg >> 2) * 512 + (((r & 15) << 2) + (cg & 3)) * 8));
    }
#pragma unroll
    for (int d = 8; d <= 32; d <<= 1) {
#pragma unroll
        for (int j = 0; j < 4; ++j) {
            sa[j] += __shfl_xor(sa[j], d); qa[j] += __shfl_xor(qa[j], d);
            sb[j] += __shfl_xor(sb[j], d); qb[j] += __shfl_xor(qb[j], d);
        }
    }
    __shared__ float red[128];
    if (tid < 128) red[tid] = 0.f;
    __syncthreads();
    if (lane < 8) {
#pragma unroll
        for (int j = 0; j < 4; ++j) {
            atomicAdd(&red[lane * 8 + j], sa[j]);
            atomicAdd(&red[lane * 8 + 4 + j], sb[j]);
            atomicAdd(&red[64 + lane * 8 + j], qa[j]);
            atomicAdd(&red[64 + lane * 8 + 4 + j], qb[j]);
        }
    }
    __syncthreads();
    if (tid < 64) atomicAdd(&sum[256 + tid], red[tid]);
    else if (tid < 128) atomicAdd(&sq[256 + tid - 64], red[tid]);
}

__global__ __launch_bounds__(256) void k_hstats(const float* __restrict__ h,
                                                const int* __restrict__ cs, const int* __restrict__ cd,
                                                float* __restrict__ sum, float* __restrict__ sq) {
    const int tid = threadIdx.x;
    const int c = tid & 127, g = tid >> 7;
    float ss = 0.f, qs = 0.f, sd = 0.f, qd = 0.f;
    for (int n = blockIdx.x * 2 + g; n < N_NODES; n += gridDim.x * 2) {
        float v = h[(size_t)n * 128 + c];
        float a = (float)cs[n], b = (float)cd[n];
        ss += a * v; qs += a * v * v;
        sd += b * v; qd += b * v * v;
    }
    __shared__ float red[256];
    red[tid] = ss; __syncthreads();
    if (tid < 128) atomicAdd(&sum[tid], red[tid] + red[tid + 128]);
    __syncthreads();
    red[tid] = qs; __syncthreads();
    if (tid < 128) atomicAdd(&sq[tid], red[tid] + red[tid + 128]);
    __syncthreads();
    red[tid] = sd; __syncthreads();
    if (tid < 128) atomicAdd(&sum[128 + tid], red[tid] + red[tid + 128]);
    __syncthreads();
    red[tid] = qd; __syncthreads();
    if (tid < 128) atomicAdd(&sq[128 + tid], red[tid] + red[tid + 128]);
}

__global__ __launch_bounds__(320) void k_fold0(const float* __restrict__ sum, const float* __restrict__ sq,
        const float* __restrict__ g0, const float* __restrict__ b0,
        float* __restrict__ scale0, float* __restrict__ shift0) {
    int j = threadIdx.x;
    if (j < 320) {
        const float invE = 1.f / (float)N_EDGES;
        float mu = sum[j] * invE;
        float var = sq[j] * invE - mu * mu;
        float sc = g0[j] * rsqrtf(var + 1e-5f);
        scale0[j] = sc;
        shift0[j] = b0[j] - mu * sc;
    }
}

__global__ __launch_bounds__(320) void k_foldW1(const float* __restrict__ W1, const float* __restrict__ b1,
        const float* __restrict__ scale0, const float* __restrict__ shift0,
        unsigned short* __restrict__ W1s, unsigned short* __restrict__ W1d,
        unsigned short* __restrict__ W1e, float* __restrict__ b1p) {
    __shared__ float sc[320], sh[320];
    const int tid = threadIdx.x;
    if (tid < 320) { sc[tid] = scale0[tid]; sh[tid] = shift0[tid]; }
    __syncthreads();
    if (tid < 256) {
        float acc = b1[tid];
        const float* wr = W1 + (size_t)tid * 320;
        for (int j = 0; j < 320; ++j) {
            float wv = wr[j];
            acc += wv * sh[j];
            unsigned short wb = f2bf(wv * sc[j]);
            if (j < 128) W1s[tid * 128 + j] = wb;
            else if (j < 256) W1d[tid * 128 + (j - 128)] = wb;
            else W1e[tid * 64 + (j - 256)] = wb;
        }
        b1p[tid] = acc;
    }
}

// P = h @ W'^T : M=50000 (256/block), N=256, K=128. Row-major bf16 output.
__global__ __launch_bounds__(256) void k_P(const float* __restrict__ h,
        const unsigned short* __restrict__ W1s, const unsigned short* __restrict__ W1d,
        unsigned short* __restrict__ Ps, unsigned short* __restrict__ Pd) {
    __shared__ unsigned short tile[16 * 264];
    const int tid = threadIdx.x;
    const int w = tid >> 6, lane = tid & 63, quad = lane >> 4, l15 = lane & 15;
    const unsigned short* W = blockIdx.y ? W1d : W1s;
    unsigned short* P = blockIdx.y ? Pd : Ps;
    const size_t base = (size_t)blockIdx.x * 256;
    bf8_t bfr[4][4];
#pragma unroll
    for (int j = 0; j < 4; ++j) {
        const unsigned short* wp = W + (size_t)((w * 4 + j) * 16 + l15) * 128 + quad * 8;
#pragma unroll
        for (int ks = 0; ks < 4; ++ks) bfr[j][ks] = *(const bf8_t*)(wp + ks * 32);
    }
    const int erow = tid >> 4, ex = tid & 15;
    for (int mc = 0; mc < 16; ++mc) {
        const size_t row0 = base + mc * 16;
        size_t ar = row0 + l15; if (ar >= N_NODES) ar = N_NODES - 1;
        const float* hp = h + ar * 128 + quad * 8;
        bf8_t af[4];
#pragma unroll
        for (int ks = 0; ks < 4; ++ks)
            af[ks] = cvt8(*(const f4_t*)(hp + ks * 32), *(const f4_t*)(hp + ks * 32 + 4));
#pragma unroll
        for (int j = 0; j < 4; ++j) {
            f4_t t = {0.f, 0.f, 0.f, 0.f};
#pragma unroll
            for (int ks = 0; ks < 4; ++ks)
                t = __builtin_amdgcn_mfma_f32_16x16x32_bf16(af[ks], bfr[j][ks], t, 0, 0, 0);
            const unsigned int p01 = cvt_pk(t[0], t[1]);
            const unsigned int p23 = cvt_pk(t[2], t[3]);
            const int col = (w * 4 + j) * 16 + l15;
            tile[(quad * 4 + 0) * 264 + col] = (unsigned short)p01;
            tile[(quad * 4 + 1) * 264 + col] = (unsigned short)(p01 >> 16);
            tile[(quad * 4 + 2) * 264 + col] = (unsigned short)p23;
            tile[(quad * 4 + 3) * 264 + col] = (unsigned short)(p23 >> 16);
        }
        __syncthreads();
        const size_t orow = row0 + erow;
        if (orow < N_NODES) {
            u4_t v0 = *(const u4_t*)(tile + erow * 264 + ex * 16);
            u4_t v1 = *(const u4_t*)(tile + erow * 264 + ex * 16 + 8);
            *(u4_t*)(P + orow * 256 + ex * 16) = v0;
            *(u4_t*)(P + orow * 256 + ex * 16 + 8) = v1;
        }
        __syncthreads();
    }
}

// Pass A: BN1 stats only, no stores. Vector-gather + f32 tile1 combine
// (double-buffered, 1 sync/mc); per-column stats in registers; cross-wave
// reduce via LDS scratch overlaid on tile1[0].
__global__ __launch_bounds__(256) void k_stats1(const unsigned short* __restrict__ ebf,
        const int* __restrict__ src, const int* __restrict__ dst,
        const unsigned short* __restrict__ Ps, const unsigned short* __restrict__ Pd,
        const unsigned short* __restrict__ W1e, const float* __restrict__ b1p,
        float* __restrict__ slots) {
    __shared__ __align__(16) float tile1[2][16 * 268];
    __shared__ int sIdx[256], dIdx[256];
    const int tid = threadIdx.x;
    const int w = tid >> 6, lane = tid & 63, quad = lane >> 4, l15 = lane & 15;
    const int perm = l15 * 4 + quad;
    const size_t base = (size_t)blockIdx.x * 256;
    const size_t blk16 = (size_t)blockIdx.x * 16;
    sIdx[tid] = src[base + tid];
    dIdx[tid] = dst[base + tid];
    bf8_t bfr1[4][2];
    float bias4[4];
#pragma unroll
    for (int j = 0; j < 4; ++j) {
        const unsigned short* wp = W1e + (size_t)((w * 4 + j) * 16 + l15) * 64 + quad * 8;
        bfr1[j][0] = *(const bf8_t*)(wp);
        bfr1[j][1] = *(const bf8_t*)(wp + 32);
        bias4[j] = b1p[(w * 4 + j) * 16 + l15];
    }
    const int erow = tid >> 4, ex = tid & 15;
    float s[16], q[16];
#pragma unroll
    for (int j = 0; j < 16; ++j) { s[j] = 0.f; q[j] = 0.f; }
    __syncthreads();  // publish sIdx/dIdx
    bf8_t af0, af1;
    u4_t gs0, gs1, gd0, gd1;
    {
        const unsigned short* ap = ebf + blk16 * 1024 + perm * 8;
        af0 = __builtin_nontemporal_load((const bf8_t*)(ap));
        af1 = __builtin_nontemporal_load((const bf8_t*)(ap + 512));
        const size_t sr = (size_t)sIdx[erow] * 256, dr = (size_t)dIdx[erow] * 256;
        gs0 = *(const u4_t*)(Ps + sr + ex * 8);
        gs1 = *(const u4_t*)(Ps + sr + ex * 8 + 128);
        gd0 = *(const u4_t*)(Pd + dr + ex * 8);
        gd1 = *(const u4_t*)(Pd + dr + ex * 8 + 128);
    }
    for (int mc = 0; mc < 16; ++mc) {
        float* t1 = tile1[mc & 1];
#pragma unroll
        for (int j = 0; j < 4; ++j) {
            f4_t t = {bias4[j], bias4[j], bias4[j], bias4[j]};
            t = __builtin_amdgcn_mfma_f32_16x16x32_bf16(af0, bfr1[j][0], t, 0, 0, 0);
            t = __builtin_amdgcn_mfma_f32_16x16x32_bf16(af1, bfr1[j][1], t, 0, 0, 0);
#pragma unroll
            for (int r = 0; r < 4; ++r)
                t1[(quad * 4 + r) * 268 + (w * 4 + j) * 16 + l15] = t[r];
        }
        if (mc < 15) {
            const unsigned short* ap = ebf + (blk16 + mc + 1) * 1024 + perm * 8;
            af0 = __builtin_nontemporal_load((const bf8_t*)(ap));
            af1 = __builtin_nontemporal_load((const bf8_t*)(ap + 512));
        }
        // One sync per mc: t1 writes complete; also orders next iter's write
        // of the other buffer behind this iter's reads of it.
        __syncthreads();
#pragma unroll
        for (int i = 0; i < 2; ++i) {
            const float* tp = t1 + erow * 268 + ex * 8 + 128 * i;
            f4_t tv0 = *(const f4_t*)tp;
            f4_t tv1 = *(const f4_t*)(tp + 4);
            const unsigned short* su = (const unsigned short*)(i ? &gs1 : &gs0);
            const unsigned short* du = (const unsigned short*)(i ? &gd1 : &gd0);
#pragma unroll
            for (int j = 0; j < 4; ++j) {
                float v = fmaxf(tv0[j] + bf2f(su[j]) + bf2f(du[j]), 0.f);
                s[i * 8 + j] += v; q[i * 8 + j] += v * v;
            }
#pragma unroll
            for (int j = 0; j < 4; ++j) {
                float v = fmaxf(tv1[j] + bf2f(su[4 + j]) + bf2f(du[4 + j]), 0.f);
                s[i * 8 + 4 + j] += v; q[i * 8 + 4 + j] += v * v;
            }
        }
        if (mc < 15) {
            const size_t sr = (size_t)sIdx[(mc + 1) * 16 + erow] * 256;
            const size_t dr = (size_t)dIdx[(mc + 1) * 16 + erow] * 256;
            gs0 = *(const u4_t*)(Ps + sr + ex * 8);
            gs1 = *(const u4_t*)(Ps + sr + ex * 8 + 128);
            gd0 = *(const u4_t*)(Pd + dr + ex * 8);
            gd1 = *(const u4_t*)(Pd + dr + ex * 8 + 128);
        }
    }
    // Reduce over this wave's 4 rows (row bits live in lane>>4).
#pragma unroll
    for (int j = 0; j < 16; ++j) {
        s[j] += __shfl_xor(s[j], 16); s[j] += __shfl_xor(s[j], 32);
        q[j] += __shfl_xor(q[j], 16); q[j] += __shfl_xor(q[j], 32);
    }
    // Cross-wave reduce via LDS scratch on tile1[0] (last read of tile1[0]
    // was mc=14, ordered behind mc=15's sync; mc=15 readers touch tile1[1]).
    float* scratch = &tile1[0][0];  // 2048 floats
    if (lane < 16) {
#pragma unroll
        for (int j = 0; j < 16; ++j) {
            scratch[(w * 16 + l15) * 16 + j] = s[j];
            scratch[1024 + (w * 16 + l15) * 16 + j] = q[j];
        }
    }
    __syncthreads();
    {
        const int c = tid;  // column 0..255
        const int idx = (c & 7) + (c >> 7) * 8;
        const int exx = (c >> 3) & 15;
        float S = 0.f, Q = 0.f;
#pragma unroll
        for (int ww = 0; ww < 4; ++ww) {
            S += scratch[(ww * 16 + exx) * 16 + idx];
            Q += scratch[1024 + (ww * 16 + exx) * 16 + idx];
        }
        float* sl = slots + (size_t)(blockIdx.x & 63) * 512;
        atomicAdd(&sl[c], S);
        atomicAdd(&sl[256 + c], Q);
    }
}

__global__ __launch_bounds__(256) void k_fold1(const float* __restrict__ slots,
        const float* __restrict__ g1, const float* __restrict__ b1n,
        const float* __restrict__ W2, const float* __restrict__ b2,
        unsigned short* __restrict__ W2p, float* __restrict__ b2p) {
    __shared__ float sc[256], sh[256];
    const int tid = threadIdx.x;
    float S = 0.f, Q = 0.f;
    for (int s = 0; s < 64; ++s) { S += slots[s * 512 + tid]; Q += slots[s * 512 + 256 + tid]; }
    const float invE = 1.f / (float)N_EDGES;
    float mu = S * invE;
    float var = Q * invE - mu * mu;
    float scl = g1[tid] * rsqrtf(var + 1e-5f);
    sc[tid] = scl; sh[tid] = b1n[tid] - mu * scl;
    __syncthreads();
    if (tid < 128) {
        float acc = b2[tid];
        const float* wr = W2 + (size_t)tid * 256;
        for (int j = 0; j < 256; ++j) {
            float wv = wr[j];
            acc += wv * sh[j];
            W2p[tid * 256 + j] = f2bf(wv * sc[j]);
        }
        b2p[tid] = acc;
    }
}

// Pass B: recompute a1 chunk (GEMM1 -> f32 tile1 -> combine) into A-tiled LDS
// (double-buffered tile2), then GEMM2 (W2p in regs) -> a2 C-cells + BN2 stats.
__global__ __launch_bounds__(256) void k_L12(const unsigned short* __restrict__ ebf,
        const int* __restrict__ src, const int* __restrict__ dst,
        const unsigned short* __restrict__ Ps, const unsigned short* __restrict__ Pd,
        const unsigned short* __restrict__ W1e, const float* __restrict__ b1p,
        const unsigned short* __restrict__ W2p, const float* __restrict__ b2p,
        unsigned short* __restrict__ a2c, float* __restrict__ slots) {
    __shared__ __align__(16) float tile1[16 * 268];
    __shared__ unsigned short tile2[2][4096];
    __shared__ int sIdx[256], dIdx[256];
    const int tid = threadIdx.x;
    const int w = tid >> 6, lane = tid & 63, quad = lane >> 4, l15 = lane & 15;
    const int perm = l15 * 4 + quad;
    const size_t base = (size_t)blockIdx.x * 256;
    const size_t blk16 = (size_t)blockIdx.x * 16;
    sIdx[tid] = src[base + tid];
    dIdx[tid] = dst[base + tid];
    bf8_t bfr1[4][2];
    float bias4[4];
#pragma unroll
    for (int j = 0; j < 4; ++j) {
        const unsigned short* wp = W1e + (size_t)((w * 4 + j) * 16 + l15) * 64 + quad * 8;
        bfr1[j][0] = *(const bf8_t*)(wp);
        bfr1[j][1] = *(const bf8_t*)(wp + 32);
        bias4[j] = b1p[(w * 4 + j) * 16 + l15];
    }
    bf8_t bfr2[2][8];
    float bias2[2];
#pragma unroll
    for (int j = 0; j < 2; ++j) {
        const unsigned short* wp = W2p + (size_t)((w * 2 + j) * 16 + l15) * 256 + quad * 8;
#pragma unroll
        for (int ks = 0; ks < 8; ++ks) bfr2[j][ks] = *(const bf8_t*)(wp + ks * 32);
        bias2[j] = b2p[(w * 2 + j) * 16 + l15];
    }
    const int erow = tid >> 4, ex = tid & 15;
    float s0 = 0.f, q0 = 0.f, s1 = 0.f, q1 = 0.f;
    __syncthreads();  // publish sIdx/dIdx
    bf8_t af0, af1;
    u4_t gs0, gs1, gd0, gd1;
    {
        const unsigned short* ap = ebf + blk16 * 1024 + perm * 8;
        af0 = __builtin_nontemporal_load((const bf8_t*)(ap));
        af1 = __builtin_nontemporal_load((const bf8_t*)(ap + 512));
        const size_t sr = (size_t)sIdx[erow] * 256, dr = (size_t)dIdx[erow] * 256;
        gs0 = *(const u4_t*)(Ps + sr + ex * 8);
        gs1 = *(const u4_t*)(Ps + sr + ex * 8 + 128);
        gd0 = *(const u4_t*)(Pd + dr + ex * 8);
        gd1 = *(const u4_t*)(Pd + dr + ex * 8 + 128);
    }
    for (int mc = 0; mc < 16; ++mc) {
        unsigned short* t2 = tile2[mc & 1];
#pragma unroll
        for (int j = 0; j < 4; ++j) {
            f4_t t = {bias4[j], bias4[j], bias4[j], bias4[j]};
            t = __builtin_amdgcn_mfma_f32_16x16x32_bf16(af0, bfr1[j][0], t, 0, 0, 0);
            t = __builtin_amdgcn_mfma_f32_16x16x32_bf16(af1, bfr1[j][1], t, 0, 0, 0);
#pragma unroll
            for (int r = 0; r < 4; ++r)
                tile1[(quad * 4 + r) * 268 + (w * 4 + j) * 16 + l15] = t[r];
        }
        if (mc < 15) {
            const unsigned short* ap = ebf + (blk16 + mc + 1) * 1024 + perm * 8;
            af0 = __builtin_nontemporal_load((const bf8_t*)(ap));
            af1 = __builtin_nontemporal_load((const bf8_t*)(ap + 512));
        }
        __syncthreads();  // tile1 complete (also: prev combine-readers done)
#pragma unroll
        for (int i = 0; i < 2; ++i) {
            const float* tp = tile1 + erow * 268 + ex * 8 + 128 * i;
            f4_t tv0 = *(const f4_t*)tp;
            f4_t tv1 = *(const f4_t*)(tp + 4);
            const unsigned short* su = (const unsigned short*)(i ? &gs1 : &gs0);
            const unsigned short* du = (const unsigned short*)(i ? &gd1 : &gd0);
            float c0 = fmaxf(tv0[0] + bf2f(su[0]) + bf2f(du[0]), 0.f);
            float c1 = fmaxf(tv0[1] + bf2f(su[1]) + bf2f(du[1]), 0.f);
            float c2 = fmaxf(tv0[2] + bf2f(su[2]) + bf2f(du[2]), 0.f);
            float c3 = fmaxf(tv0[3] + bf2f(su[3]) + bf2f(du[3]), 0.f);
            float c4 = fmaxf(tv1[0] + bf2f(su[4]) + bf2f(du[4]), 0.f);
            float c5 = fmaxf(tv1[1] + bf2f(su[5]) + bf2f(du[5]), 0.f);
            float c6 = fmaxf(tv1[2] + bf2f(su[6]) + bf2f(du[6]), 0.f);
            float c7 = fmaxf(tv1[3] + bf2f(su[7]) + bf2f(du[7]), 0.f);
            u4_t ov;
            ov[0] = cvt_pk(c0, c1);
            ov[1] = cvt_pk(c2, c3);
            ov[2] = cvt_pk(c4, c5);
            ov[3] = cvt_pk(c6, c7);
            *(u4_t*)(&t2[((ex >> 2) + 4 * i) * 512 + (erow * 4 + (ex & 3)) * 8]) = ov;
        }
        if (mc < 15) {
            const size_t sr = (size_t)sIdx[(mc + 1) * 16 + erow] * 256;
            const size_t dr = (size_t)dIdx[(mc + 1) * 16 + erow] * 256;
            gs0 = *(const u4_t*)(Ps + sr + ex * 8);
            gs1 = *(const u4_t*)(Ps + sr + ex * 8 + 128);
            gd0 = *(const u4_t*)(Pd + dr + ex * 8);
            gd1 = *(const u4_t*)(Pd + dr + ex * 8 + 128);
        }
        __syncthreads();  // tile2[buf] complete
        f4_t acc0 = {bias2[0], bias2[0], bias2[0], bias2[0]};
        f4_t acc1 = {bias2[1], bias2[1], bias2[1], bias2[1]};
#pragma unroll
        for (int ks = 0; ks < 8; ++ks) {
            bf8_t a = *(const bf8_t*)(&t2[ks * 512 + perm * 8]);
            acc0 = __builtin_amdgcn_mfma_f32_16x16x32_bf16(a, bfr2[0][ks], acc0, 0, 0, 0);
            acc1 = __builtin_amdgcn_mfma_f32_16x16x32_bf16(a, bfr2[1][ks], acc1, 0, 0, 0);
        }
        unsigned short* outp = a2c + (blk16 + mc) * 2048;
        {
            float v0 = fmaxf(acc0[0], 0.f), v1 = fmaxf(acc0[1], 0.f);
            float v2 = fmaxf(acc0[2], 0.f), v3 = fmaxf(acc0[3], 0.f);
            s0 += v0; q0 += v0 * v0; s0 += v1; q0 += v1 * v1;
            s0 += v2; q0 += v2 * v2; s0 += v3; q0 += v3 * v3;
            u2_t pw; pw[0] = cvt_pk(v0, v1); pw[1] = cvt_pk(v2, v3);
            __builtin_nontemporal_store(pw,
                (u2_t*)(outp + (((w * 2) * 16 + l15) * 4 + quad) * 4));
        }
        {
            float v0 = fmaxf(acc1[0], 0.f), v1 = fmaxf(acc1[1], 0.f);
            float v2 = fmaxf(acc1[2], 0.f), v3 = fmaxf(acc1[3], 0.f);
            s1 += v0; q1 += v0 * v0; s1 += v1; q1 += v1 * v1;
            s1 += v2; q1 += v2 * v2; s1 += v3; q1 += v3 * v3;
            u2_t pw; pw[0] = cvt_pk(v0, v1); pw[1] = cvt_pk(v2, v3);
            __builtin_nontemporal_store(pw,
                (u2_t*)(outp + (((w * 2 + 1) * 16 + l15) * 4 + quad) * 4));
        }
    }
    s0 += __shfl_xor(s0, 16); s0 += __shfl_xor(s0, 32);
    q0 += __shfl_xor(q0, 16); q0 += __shfl_xor(q0, 32);
    s1 += __shfl_xor(s1, 16); s1 += __shfl_xor(s1, 32);
    q1 += __shfl_xor(q1, 16); q1 += __shfl_xor(q1, 32);
    if (lane < 16) {
        float* sl = slots + (size_t)(blockIdx.x & 63) * 256;
        const int c0 = (w * 2) * 16 + l15;
        atomicAdd(&sl[c0], s0); atomicAdd(&sl[128 + c0], q0);
        atomicAdd(&sl[c0 + 16], s1); atomicAdd(&sl[128 + c0 + 16], q1);
    }
}

__global__ __launch_bounds__(128) void k_fold2(const float* __restrict__ slots,
        const float* __restrict__ g2, const float* __restrict__ b2n,
        const float* __restrict__ W3, const float* __restrict__ b3,
        float* __restrict__ w3p, float* __restrict__ b3p) {
    __shared__ float red[128];
    const int tid = threadIdx.x;
    float S = 0.f, Q = 0.f;
    for (int s = 0; s < 64; ++s) { S += slots[s * 256 + tid]; Q += slots[s * 256 + 128 + tid]; }
    const float invE = 1.f / (float)N_EDGES;
    float mu = S * invE;
    float var = Q * invE - mu * mu;
    float scl = g2[tid] * rsqrtf(var + 1e-5f);
    float shf = b2n[tid] - mu * scl;
    w3p[tid] = W3[tid] * scl;
    red[tid] = W3[tid] * shf;
    __syncthreads();
    for (int st = 64; st > 0; st >>= 1) {
        if (tid < st) red[tid] += red[tid + st];
        __syncthreads();
    }
    if (tid == 0) b3p[0] = b3[0] + red[0];
}

// out = a2 . w3' + b3' from C-layout cells; wave per 16-row block, shuffle reduce.
__global__ __launch_bounds__(256) void k_L3(const unsigned short* __restrict__ a2c,
        const float* __restrict__ w3p, const float* __restrict__ b3p, float* __restrict__ out) {
    __shared__ float wl[128];
    const int tid = threadIdx.x;
    if (tid < 128) wl[tid] = w3p[tid];
    __syncthreads();
    const int w = tid >> 6, lane = tid & 63, q = lane >> 4, c = lane & 15;
    const float bb = b3p[0];
#pragma unroll
    for (int i = 0; i < 4; ++i) {
        const size_t b = (size_t)blockIdx.x * 16 + w * 4 + i;
        const unsigned short* bp = a2c + b * 2048 + c * 16 + q * 4;
        float a0 = 0.f, a1r = 0.f, a2r = 0.f, a3r = 0.f;
#pragma unroll
        for (int jt = 0; jt < 8; ++jt) {
            u2_t v = __builtin_nontemporal_load((const u2_t*)(bp + jt * 256));
            const unsigned short* u = (const unsigned short*)&v;
            const float wv = wl[jt * 16 + c];
            a0 += bf2f(u[0]) * wv; a1r += bf2f(u[1]) * wv;
            a2r += bf2f(u[2]) * wv; a3r += bf2f(u[3]) * wv;
        }
#pragma unroll
        for (int d = 1; d <= 8; d <<= 1) {
            a0 += __shfl_xor(a0, d); a1r += __shfl_xor(a1r, d);
            a2r += __shfl_xor(a2r, d); a3r += __shfl_xor(a3r, d);
        }
        if (c == 0) {
            f4_t o = {a0 + bb, a1r + bb, a2r + bb, a3r + bb};
            *(f4_t*)(out + b * 16 + q * 4) = o;
        }
    }
}

extern "C" void kernel_launch(void* const* d_in, const int* in_sizes, int n_in,
                              void* d_out, int out_size, void* d_ws, size_t ws_size,
                              hipStream_t stream) {
    (void)in_sizes; (void)n_in; (void)out_size; (void)ws_size;
    const float* h   = (const float*)d_in[0];
    const float* e   = (const float*)d_in[1];
    const int*   src = (const int*)d_in[2];
    const int*   dst = (const int*)d_in[3];
    const float* bn0_g = (const float*)d_in[4];
    const float* bn0_b = (const float*)d_in[5];
    const float* W1 = (const float*)d_in[6];
    const float* b1 = (const float*)d_in[7];
    const float* bn1_g = (const float*)d_in[8];
    const float* bn1_b = (const float*)d_in[9];
    const float* W2 = (const float*)d_in[10];
    const float* b2 = (const float*)d_in[11];
    const float* bn2_g = (const float*)d_in[12];
    const float* bn2_b = (const float*)d_in[13];
    const float* W3 = (const float*)d_in[14];
    const float* b3 = (const float*)d_in[15];

    char* ws = (char*)d_ws;
    size_t off = 0;
    auto alloc = [&](size_t bytes) { char* p = ws + off; off += (bytes + 255) & ~(size_t)255; return p; };
    int*   cnt_s = (int*)alloc((size_t)N_NODES * 4);
    int*   cnt_d = (int*)alloc((size_t)N_NODES * 4);
    float* bn0_sum = (float*)alloc(320 * 4);
    float* bn0_sq  = (float*)alloc(320 * 4);
    float* bn1_slots = (float*)alloc(64 * 512 * 4);
    float* bn2_slots = (float*)alloc(64 * 256 * 4);
    const size_t zero_end = off;
    float* scale0 = (float*)alloc(320 * 4);
    float* shift0 = (float*)alloc(320 * 4);
    unsigned short* W1s = (unsigned short*)alloc(256 * 128 * 2);
    unsigned short* W1d = (unsigned short*)alloc(256 * 128 * 2);
    unsigned short* W1e = (unsigned short*)alloc(256 * 64 * 2);
    float* b1p = (float*)alloc(256 * 4);
    unsigned short* W2p = (unsigned short*)alloc(128 * 256 * 2);
    float* b2p = (float*)alloc(128 * 4);
    float* w3p = (float*)alloc(128 * 4);
    float* b3p = (float*)alloc(4);
    unsigned short* Ps = (unsigned short*)alloc((size_t)N_NODES * 256 * 2);
    unsigned short* Pd = (unsigned short*)alloc((size_t)N_NODES * 256 * 2);
    unsigned short* ebf = (unsigned short*)alloc((size_t)(N_EDGES / 16) * 2048); // 102.4 MB
    unsigned short* a2c = (unsigned short*)alloc((size_t)(N_EDGES / 16) * 4096); // 204.8 MB

    hipMemsetAsync(d_ws, 0, zero_end, stream);
    k_hist<<<(N_EDGES + 255) / 256, 256, 0, stream>>>(src, dst, cnt_s, cnt_d);
    k_ecvt<<<1024, 256, 0, stream>>>(e, ebf, bn0_sum, bn0_sq);
    k_hstats<<<400, 256, 0, stream>>>(h, cnt_s, cnt_d, bn0_sum, bn0_sq);
    k_fold0<<<1, 320, 0, stream>>>(bn0_sum, bn0_sq, bn0_g, bn0_b, scale0, shift0);
    k_foldW1<<<1, 320, 0, stream>>>(W1, b1, scale0, shift0, W1s, W1d, W1e, b1p);
    k_P<<<dim3(196, 2), 256, 0, stream>>>(h, W1s, W1d, Ps, Pd);
    k_stats1<<<N_EDGES / 256, 256, 0, stream>>>(ebf, src, dst, Ps, Pd, W1e, b1p, bn1_slots);
    k_fold1<<<1, 256, 0, stream>>>(bn1_slots, bn1_g, bn1_b, W2, b2, W2p, b2p);
    k_L12<<<N_EDGES / 256, 256, 0, stream>>>(ebf, src, dst, Ps, Pd, W1e, b1p, W2p, b2p, a2c, bn2_slots);
    k_fold2<<<1, 128, 0, stream>>>(bn2_slots, bn2_g, bn2_b, W3, b3, w3p, b3p);
    k_L3<<<N_EDGES / 256, 256, 0, stream>>>(a2c, w3p, b3p, (float*)d_out);
}

// Round 7
// 974.633 us; speedup vs baseline: 1.0959x; 1.0129x over previous
//
#include <hip/hip_runtime.h>

// NNPredictor: edge MLP with BN folded into weights.
// R16 = R15 + LDS-residency push (k_L12 latency-bound: no pipe >41%,
// occupancy 20.7% despite nominal 4 blocks/CU; R10 showed LDS 27KB <-> 40%):
//   - k_L12: bf16 tile1 (stride 264, cvt_pk write) + SINGLE-buffered tile2
//     (double-buffer provably redundant given the 2 syncs) -> LDS 18688.
//   - k_stats1: bf16 tile1[2] -> LDS ~18944.
//   - k_L12 split into two half-grid launches (visibility: unmask stats1).
//   - k_hist fused into k_ecvt; k_fold0 fused into k_foldW1 (11->10 launches).

#define N_EDGES 800000
#define N_NODES 50000

typedef __attribute__((ext_vector_type(8))) short bf8_t;
typedef __attribute__((ext_vector_type(4))) float f4_t;
typedef __attribute__((ext_vector_type(2))) unsigned int u2_t;
typedef __attribute__((ext_vector_type(4))) unsigned int u4_t;

__device__ __forceinline__ unsigned short f2bf(float f) {
    unsigned int u = __builtin_bit_cast(unsigned int, f);
    u += 0x7FFFu + ((u >> 16) & 1u);
    return (unsigned short)(u >> 16);
}
__device__ __forceinline__ float bf2f(unsigned short s) {
    unsigned int u = ((unsigned int)s) << 16;
    return __builtin_bit_cast(float, u);
}
// Packed f32x2 -> bf16x2 (RTNE), lo in [15:0], hi in [31:16].
__device__ __forceinline__ unsigned int cvt_pk(float lo, float hi) {
    unsigned int r;
    asm("v_cvt_pk_bf16_f32 %0, %1, %2" : "=v"(r) : "v"(lo), "v"(hi));
    return r;
}
__device__ __forceinline__ bf8_t cvt8(f4_t x, f4_t y) {
    union { unsigned int u[4]; bf8_t v; } r;
    r.u[0] = cvt_pk(x[0], x[1]);
    r.u[1] = cvt_pk(x[2], x[3]);
    r.u[2] = cvt_pk(y[0], y[1]);
    r.u[3] = cvt_pk(y[2], y[3]);
    return r.v;
}

// e -> bf16 A-tiled [blk16][ks(2)][(row*4+colgrp)][8] + BN0 e-col stats
// + fused degree histogram (cg==0 thread per row).
__global__ __launch_bounds__(256) void k_ecvt(const float* __restrict__ e,
        const int* __restrict__ src, const int* __restrict__ dst,
        unsigned short* __restrict__ ebf, int* __restrict__ cs, int* __restrict__ cd,
        float* __restrict__ sum, float* __restrict__ sq) {
    const int tid = threadIdx.x;
    const int lane = tid & 63;
    const int cg = tid & 7, rr = tid >> 3;
    f4_t sa = {0.f,0.f,0.f,0.f}, sb = sa, qa = sa, qb = sa;
    for (int r = blockIdx.x * 32 + rr; r < N_EDGES; r += gridDim.x * 32) {
        f4_t va = __builtin_nontemporal_load((const f4_t*)(e + (size_t)r * 64 + cg * 8));
        f4_t vb = __builtin_nontemporal_load((const f4_t*)(e + (size_t)r * 64 + cg * 8 + 4));
        sa += va; qa += va * va; sb += vb; qb += vb * vb;
        bf8_t o = cvt8(va, vb);
        __builtin_nontemporal_store(o,
            (bf8_t*)(ebf + (size_t)(r >> 4) * 1024 + (cg >> 2) * 512 + (((r & 15) << 2) + (cg & 3)) * 8));
        if (cg == 0) {
            atomicAdd(&cs[src[r]], 1);
            atomicAdd(&cd[dst[r]], 1);
        }
    }
#pragma unroll
    for (int d = 8; d <= 32; d <<= 1) {
#pragma unroll
        for (int j = 0; j < 4; ++j) {
            sa[j] += __shfl_xor(sa[j], d); qa[j] += __shfl_xor(qa[j], d);
            sb[j] += __shfl_xor(sb[j], d); qb[j] += __shfl_xor(qb[j], d);
        }
    }
    __shared__ float red[128];
    if (tid < 128) red[tid] = 0.f;
    __syncthreads();
    if (lane < 8) {
#pragma unroll
        for (int j = 0; j < 4; ++j) {
            atomicAdd(&red[lane * 8 + j], sa[j]);
            atomicAdd(&red[lane * 8 + 4 + j], sb[j]);
            atomicAdd(&red[64 + lane * 8 + j], qa[j]);
            atomicAdd(&red[64 + lane * 8 + 4 + j], qb[j]);
        }
    }
    __syncthreads();
    if (tid < 64) atomicAdd(&sum[256 + tid], red[tid]);
    else if (tid < 128) atomicAdd(&sq[256 + tid - 64], red[tid]);
}

__global__ __launch_bounds__(256) void k_hstats(const float* __restrict__ h,
                                                const int* __restrict__ cs, const int* __restrict__ cd,
                                                float* __restrict__ sum, float* __restrict__ sq) {
    const int tid = threadIdx.x;
    const int c = tid & 127, g = tid >> 7;
    float ss = 0.f, qs = 0.f, sd = 0.f, qd = 0.f;
    for (int n = blockIdx.x * 2 + g; n < N_NODES; n += gridDim.x * 2) {
        float v = h[(size_t)n * 128 + c];
        float a = (float)cs[n], b = (float)cd[n];
        ss += a * v; qs += a * v * v;
        sd += b * v; qd += b * v * v;
    }
    __shared__ float red[256];
    red[tid] = ss; __syncthreads();
    if (tid < 128) atomicAdd(&sum[tid], red[tid] + red[tid + 128]);
    __syncthreads();
    red[tid] = qs; __syncthreads();
    if (tid < 128) atomicAdd(&sq[tid], red[tid] + red[tid + 128]);
    __syncthreads();
    red[tid] = sd; __syncthreads();
    if (tid < 128) atomicAdd(&sum[128 + tid], red[tid] + red[tid + 128]);
    __syncthreads();
    red[tid] = qd; __syncthreads();
    if (tid < 128) atomicAdd(&sq[128 + tid], red[tid] + red[tid + 128]);
}

// fold0 fused: compute BN0 scale/shift in LDS, then fold into W1 / split.
__global__ __launch_bounds__(320) void k_foldW1(const float* __restrict__ sum, const float* __restrict__ sq,
        const float* __restrict__ g0, const float* __restrict__ b0,
        const float* __restrict__ W1, const float* __restrict__ b1,
        unsigned short* __restrict__ W1s, unsigned short* __restrict__ W1d,
        unsigned short* __restrict__ W1e, float* __restrict__ b1p) {
    __shared__ float sc[320], sh[320];
    const int tid = threadIdx.x;
    if (tid < 320) {
        const float invE = 1.f / (float)N_EDGES;
        float mu = sum[tid] * invE;
        float var = sq[tid] * invE - mu * mu;
        float scl = g0[tid] * rsqrtf(var + 1e-5f);
        sc[tid] = scl;
        sh[tid] = b0[tid] - mu * scl;
    }
    __syncthreads();
    if (tid < 256) {
        float acc = b1[tid];
        const float* wr = W1 + (size_t)tid * 320;
        for (int j = 0; j < 320; ++j) {
            float wv = wr[j];
            acc += wv * sh[j];
            unsigned short wb = f2bf(wv * sc[j]);
            if (j < 128) W1s[tid * 128 + j] = wb;
            else if (j < 256) W1d[tid * 128 + (j - 128)] = wb;
            else W1e[tid * 64 + (j - 256)] = wb;
        }
        b1p[tid] = acc;
    }
}

// P = h @ W'^T : M=50000 (256/block), N=256, K=128. Row-major bf16 output.
__global__ __launch_bounds__(256) void k_P(const float* __restrict__ h,
        const unsigned short* __restrict__ W1s, const unsigned short* __restrict__ W1d,
        unsigned short* __restrict__ Ps, unsigned short* __restrict__ Pd) {
    __shared__ unsigned short tile[16 * 264];
    const int tid = threadIdx.x;
    const int w = tid >> 6, lane = tid & 63, quad = lane >> 4, l15 = lane & 15;
    const unsigned short* W = blockIdx.y ? W1d : W1s;
    unsigned short* P = blockIdx.y ? Pd : Ps;
    const size_t base = (size_t)blockIdx.x * 256;
    bf8_t bfr[4][4];
#pragma unroll
    for (int j = 0; j < 4; ++j) {
        const unsigned short* wp = W + (size_t)((w * 4 + j) * 16 + l15) * 128 + quad * 8;
#pragma unroll
        for (int ks = 0; ks < 4; ++ks) bfr[j][ks] = *(const bf8_t*)(wp + ks * 32);
    }
    const int erow = tid >> 4, ex = tid & 15;
    for (int mc = 0; mc < 16; ++mc) {
        const size_t row0 = base + mc * 16;
        size_t ar = row0 + l15; if (ar >= N_NODES) ar = N_NODES - 1;
        const float* hp = h + ar * 128 + quad * 8;
        bf8_t af[4];
#pragma unroll
        for (int ks = 0; ks < 4; ++ks)
            af[ks] = cvt8(*(const f4_t*)(hp + ks * 32), *(const f4_t*)(hp + ks * 32 + 4));
#pragma unroll
        for (int j = 0; j < 4; ++j) {
            f4_t t = {0.f, 0.f, 0.f, 0.f};
#pragma unroll
            for (int ks = 0; ks < 4; ++ks)
                t = __builtin_amdgcn_mfma_f32_16x16x32_bf16(af[ks], bfr[j][ks], t, 0, 0, 0);
            const unsigned int p01 = cvt_pk(t[0], t[1]);
            const unsigned int p23 = cvt_pk(t[2], t[3]);
            const int col = (w * 4 + j) * 16 + l15;
            tile[(quad * 4 + 0) * 264 + col] = (unsigned short)p01;
            tile[(quad * 4 + 1) * 264 + col] = (unsigned short)(p01 >> 16);
            tile[(quad * 4 + 2) * 264 + col] = (unsigned short)p23;
            tile[(quad * 4 + 3) * 264 + col] = (unsigned short)(p23 >> 16);
        }
        __syncthreads();
        const size_t orow = row0 + erow;
        if (orow < N_NODES) {
            u4_t v0 = *(const u4_t*)(tile + erow * 264 + ex * 16);
            u4_t v1 = *(const u4_t*)(tile + erow * 264 + ex * 16 + 8);
            *(u4_t*)(P + orow * 256 + ex * 16) = v0;
            *(u4_t*)(P + orow * 256 + ex * 16 + 8) = v1;
        }
        __syncthreads();
    }
}

// Pass A: BN1 stats only. Vector-gather + bf16 tile1 combine (double-buffered,
// 1 sync/mc); per-column stats in registers; cross-wave reduce via f32 LDS
// scratch overlaid on tile1[0] (8448B >= 8192B needed).
__global__ __launch_bounds__(256) void k_stats1(const unsigned short* __restrict__ ebf,
        const int* __restrict__ src, const int* __restrict__ dst,
        const unsigned short* __restrict__ Ps, const unsigned short* __restrict__ Pd,
        const unsigned short* __restrict__ W1e, const float* __restrict__ b1p,
        float* __restrict__ slots) {
    __shared__ __align__(16) unsigned short tile1[2][16 * 264];
    __shared__ int sIdx[256], dIdx[256];
    const int tid = threadIdx.x;
    const int w = tid >> 6, lane = tid & 63, quad = lane >> 4, l15 = lane & 15;
    const int perm = l15 * 4 + quad;
    const size_t base = (size_t)blockIdx.x * 256;
    const size_t blk16 = (size_t)blockIdx.x * 16;
    sIdx[tid] = src[base + tid];
    dIdx[tid] = dst[base + tid];
    bf8_t bfr1[4][2];
    float bias4[4];
#pragma unroll
    for (int j = 0; j < 4; ++j) {
        const unsigned short* wp = W1e + (size_t)((w * 4 + j) * 16 + l15) * 64 + quad * 8;
        bfr1[j][0] = *(const bf8_t*)(wp);
        bfr1[j][1] = *(const bf8_t*)(wp + 32);
        bias4[j] = b1p[(w * 4 + j) * 16 + l15];
    }
    const int erow = tid >> 4, ex = tid & 15;
    float s[16], q[16];
#pragma unroll
    for (int j = 0; j < 16; ++j) { s[j] = 0.f; q[j] = 0.f; }
    __syncthreads();  // publish sIdx/dIdx
    bf8_t af0, af1;
    u4_t gs0, gs1, gd0, gd1;
    {
        const unsigned short* ap = ebf + blk16 * 1024 + perm * 8;
        af0 = __builtin_nontemporal_load((const bf8_t*)(ap));
        af1 = __builtin_nontemporal_load((const bf8_t*)(ap + 512));
        const size_t sr = (size_t)sIdx[erow] * 256, dr = (size_t)dIdx[erow] * 256;
        gs0 = *(const u4_t*)(Ps + sr + ex * 8);
        gs1 = *(const u4_t*)(Ps + sr + ex * 8 + 128);
        gd0 = *(const u4_t*)(Pd + dr + ex * 8);
        gd1 = *(const u4_t*)(Pd + dr + ex * 8 + 128);
    }
    for (int mc = 0; mc < 16; ++mc) {
        unsigned short* t1 = tile1[mc & 1];
#pragma unroll
        for (int j = 0; j < 4; ++j) {
            f4_t t = {bias4[j], bias4[j], bias4[j], bias4[j]};
            t = __builtin_amdgcn_mfma_f32_16x16x32_bf16(af0, bfr1[j][0], t, 0, 0, 0);
            t = __builtin_amdgcn_mfma_f32_16x16x32_bf16(af1, bfr1[j][1], t, 0, 0, 0);
            const unsigned int p01 = cvt_pk(t[0], t[1]);
            const unsigned int p23 = cvt_pk(t[2], t[3]);
            const int col = (w * 4 + j) * 16 + l15;
            t1[(quad * 4 + 0) * 264 + col] = (unsigned short)p01;
            t1[(quad * 4 + 1) * 264 + col] = (unsigned short)(p01 >> 16);
            t1[(quad * 4 + 2) * 264 + col] = (unsigned short)p23;
            t1[(quad * 4 + 3) * 264 + col] = (unsigned short)(p23 >> 16);
        }
        if (mc < 15) {
            const unsigned short* ap = ebf + (blk16 + mc + 1) * 1024 + perm * 8;
            af0 = __builtin_nontemporal_load((const bf8_t*)(ap));
            af1 = __builtin_nontemporal_load((const bf8_t*)(ap + 512));
        }
        // One sync per mc: t1 writes complete; also orders next iter's write
        // of the other buffer behind this iter's reads of it.
        __syncthreads();
#pragma unroll
        for (int i = 0; i < 2; ++i) {
            u4_t tv = *(const u4_t*)(t1 + erow * 264 + ex * 8 + 128 * i);
            const unsigned short* tu = (const unsigned short*)&tv;
            const unsigned short* su = (const unsigned short*)(i ? &gs1 : &gs0);
            const unsigned short* du = (const unsigned short*)(i ? &gd1 : &gd0);
#pragma unroll
            for (int j = 0; j < 8; ++j) {
                float v = fmaxf(bf2f(tu[j]) + bf2f(su[j]) + bf2f(du[j]), 0.f);
                s[i * 8 + j] += v; q[i * 8 + j] += v * v;
            }
        }
        if (mc < 15) {
            const size_t sr = (size_t)sIdx[(mc + 1) * 16 + erow] * 256;
            const size_t dr = (size_t)dIdx[(mc + 1) * 16 + erow] * 256;
            gs0 = *(const u4_t*)(Ps + sr + ex * 8);
            gs1 = *(const u4_t*)(Ps + sr + ex * 8 + 128);
            gd0 = *(const u4_t*)(Pd + dr + ex * 8);
            gd1 = *(const u4_t*)(Pd + dr + ex * 8 + 128);
        }
    }
    // Reduce over this wave's 4 rows (row bits live in lane>>4).
#pragma unroll
    for (int j = 0; j < 16; ++j) {
        s[j] += __shfl_xor(s[j], 16); s[j] += __shfl_xor(s[j], 32);
        q[j] += __shfl_xor(q[j], 16); q[j] += __shfl_xor(q[j], 32);
    }
    // Cross-wave reduce via f32 scratch on tile1[0] (mc=15 readers used
    // tile1[1]; no sync needed before these writes).
    float* scratch = (float*)&tile1[0][0];  // 2048 floats, fits in 2x8448B
    if (lane < 16) {
#pragma unroll
        for (int j = 0; j < 16; ++j) {
            scratch[(w * 16 + l15) * 16 + j] = s[j];
            scratch[1024 + (w * 16 + l15) * 16 + j] = q[j];
        }
    }
    __syncthreads();
    {
        const int c = tid;  // column 0..255
        const int idx = (c & 7) + (c >> 7) * 8;
        const int exx = (c >> 3) & 15;
        float S = 0.f, Q = 0.f;
#pragma unroll
        for (int ww = 0; ww < 4; ++ww) {
            S += scratch[(ww * 16 + exx) * 16 + idx];
            Q += scratch[1024 + (ww * 16 + exx) * 16 + idx];
        }
        float* sl = slots + (size_t)(blockIdx.x & 63) * 512;
        atomicAdd(&sl[c], S);
        atomicAdd(&sl[256 + c], Q);
    }
}

__global__ __launch_bounds__(256) void k_fold1(const float* __restrict__ slots,
        const float* __restrict__ g1, const float* __restrict__ b1n,
        const float* __restrict__ W2, const float* __restrict__ b2,
        unsigned short* __restrict__ W2p, float* __restrict__ b2p) {
    __shared__ float sc[256], sh[256];
    const int tid = threadIdx.x;
    float S = 0.f, Q = 0.f;
    for (int s = 0; s < 64; ++s) { S += slots[s * 512 + tid]; Q += slots[s * 512 + 256 + tid]; }
    const float invE = 1.f / (float)N_EDGES;
    float mu = S * invE;
    float var = Q * invE - mu * mu;
    float scl = g1[tid] * rsqrtf(var + 1e-5f);
    sc[tid] = scl; sh[tid] = b1n[tid] - mu * scl;
    __syncthreads();
    if (tid < 128) {
        float acc = b2[tid];
        const float* wr = W2 + (size_t)tid * 256;
        for (int j = 0; j < 256; ++j) {
            float wv = wr[j];
            acc += wv * sh[j];
            W2p[tid * 256 + j] = f2bf(wv * sc[j]);
        }
        b2p[tid] = acc;
    }
}

// Pass B: recompute a1 chunk (GEMM1 -> bf16 tile1 -> combine) into A-tiled LDS
// (single-buffered tile2; sync1 orders next combine-write after all GEMM2
// reads, sync2 protects tile1 reuse), then GEMM2 -> a2 C-cells + BN2 stats.
__global__ __launch_bounds__(256) void k_L12(const unsigned short* __restrict__ ebf,
        const int* __restrict__ src, const int* __restrict__ dst,
        const unsigned short* __restrict__ Ps, const unsigned short* __restrict__ Pd,
        const unsigned short* __restrict__ W1e, const float* __restrict__ b1p,
        const unsigned short* __restrict__ W2p, const float* __restrict__ b2p,
        unsigned short* __restrict__ a2c, float* __restrict__ slots, const int bofs) {
    __shared__ __align__(16) unsigned short tile1[16 * 264];
    __shared__ __align__(16) unsigned short tile2[4096];
    __shared__ int sIdx[256], dIdx[256];
    const int tid = threadIdx.x;
    const int w = tid >> 6, lane = tid & 63, quad = lane >> 4, l15 = lane & 15;
    const int perm = l15 * 4 + quad;
    const int bid = bofs + blockIdx.x;
    const size_t base = (size_t)bid * 256;
    const size_t blk16 = (size_t)bid * 16;
    sIdx[tid] = src[base + tid];
    dIdx[tid] = dst[base + tid];
    bf8_t bfr1[4][2];
    float bias4[4];
#pragma unroll
    for (int j = 0; j < 4; ++j) {
        const unsigned short* wp = W1e + (size_t)((w * 4 + j) * 16 + l15) * 64 + quad * 8;
        bfr1[j][0] = *(const bf8_t*)(wp);
        bfr1[j][1] = *(const bf8_t*)(wp + 32);
        bias4[j] = b1p[(w * 4 + j) * 16 + l15];
    }
    bf8_t bfr2[2][8];
    float bias2[2];
#pragma unroll
    for (int j = 0; j < 2; ++j) {
        const unsigned short* wp = W2p + (size_t)((w * 2 + j) * 16 + l15) * 256 + quad * 8;
#pragma unroll
        for (int ks = 0; ks < 8; ++ks) bfr2[j][ks] = *(const bf8_t*)(wp + ks * 32);
        bias2[j] = b2p[(w * 2 + j) * 16 + l15];
    }
    const int erow = tid >> 4, ex = tid & 15;
    float s0 = 0.f, q0 = 0.f, s1 = 0.f, q1 = 0.f;
    __syncthreads();  // publish sIdx/dIdx
    bf8_t af0, af1;
    u4_t gs0, gs1, gd0, gd1;
    {
        const unsigned short* ap = ebf + blk16 * 1024 + perm * 8;
        af0 = __builtin_nontemporal_load((const bf8_t*)(ap));
        af1 = __builtin_nontemporal_load((const bf8_t*)(ap + 512));
        const size_t sr = (size_t)sIdx[erow] * 256, dr = (size_t)dIdx[erow] * 256;
        gs0 = *(const u4_t*)(Ps + sr + ex * 8);
        gs1 = *(const u4_t*)(Ps + sr + ex * 8 + 128);
        gd0 = *(const u4_t*)(Pd + dr + ex * 8);
        gd1 = *(const u4_t*)(Pd + dr + ex * 8 + 128);
    }
    for (int mc = 0; mc < 16; ++mc) {
#pragma unroll
        for (int j = 0; j < 4; ++j) {
            f4_t t = {bias4[j], bias4[j], bias4[j], bias4[j]};
            t = __builtin_amdgcn_mfma_f32_16x16x32_bf16(af0, bfr1[j][0], t, 0, 0, 0);
            t = __builtin_amdgcn_mfma_f32_16x16x32_bf16(af1, bfr1[j][1], t, 0, 0, 0);
            const unsigned int p01 = cvt_pk(t[0], t[1]);
            const unsigned int p23 = cvt_pk(t[2], t[3]);
            const int col = (w * 4 + j) * 16 + l15;
            tile1[(quad * 4 + 0) * 264 + col] = (unsigned short)p01;
            tile1[(quad * 4 + 1) * 264 + col] = (unsigned short)(p01 >> 16);
            tile1[(quad * 4 + 2) * 264 + col] = (unsigned short)p23;
            tile1[(quad * 4 + 3) * 264 + col] = (unsigned short)(p23 >> 16);
        }
        if (mc < 15) {
            const unsigned short* ap = ebf + (blk16 + mc + 1) * 1024 + perm * 8;
            af0 = __builtin_nontemporal_load((const bf8_t*)(ap));
            af1 = __builtin_nontemporal_load((const bf8_t*)(ap + 512));
        }
        __syncthreads();  // sync1: tile1 ready; all prev GEMM2 t2-reads done
#pragma unroll
        for (int i = 0; i < 2; ++i) {
            u4_t tv = *(const u4_t*)(tile1 + erow * 264 + ex * 8 + 128 * i);
            const unsigned short* tu = (const unsigned short*)&tv;
            const unsigned short* su = (const unsigned short*)(i ? &gs1 : &gs0);
            const unsigned short* du = (const unsigned short*)(i ? &gd1 : &gd0);
            float c0 = fmaxf(bf2f(tu[0]) + bf2f(su[0]) + bf2f(du[0]), 0.f);
            float c1 = fmaxf(bf2f(tu[1]) + bf2f(su[1]) + bf2f(du[1]), 0.f);
            float c2 = fmaxf(bf2f(tu[2]) + bf2f(su[2]) + bf2f(du[2]), 0.f);
            float c3 = fmaxf(bf2f(tu[3]) + bf2f(su[3]) + bf2f(du[3]), 0.f);
            float c4 = fmaxf(bf2f(tu[4]) + bf2f(su[4]) + bf2f(du[4]), 0.f);
            float c5 = fmaxf(bf2f(tu[5]) + bf2f(su[5]) + bf2f(du[5]), 0.f);
            float c6 = fmaxf(bf2f(tu[6]) + bf2f(su[6]) + bf2f(du[6]), 0.f);
            float c7 = fmaxf(bf2f(tu[7]) + bf2f(su[7]) + bf2f(du[7]), 0.f);
            u4_t ov;
            ov[0] = cvt_pk(c0, c1);
            ov[1] = cvt_pk(c2, c3);
            ov[2] = cvt_pk(c4, c5);
            ov[3] = cvt_pk(c6, c7);
            *(u4_t*)(&tile2[((ex >> 2) + 4 * i) * 512 + (erow * 4 + (ex & 3)) * 8]) = ov;
        }
        if (mc < 15) {
            const size_t sr = (size_t)sIdx[(mc + 1) * 16 + erow] * 256;
            const size_t dr = (size_t)dIdx[(mc + 1) * 16 + erow] * 256;
            gs0 = *(const u4_t*)(Ps + sr + ex * 8);
            gs1 = *(const u4_t*)(Ps + sr + ex * 8 + 128);
            gd0 = *(const u4_t*)(Pd + dr + ex * 8);
            gd1 = *(const u4_t*)(Pd + dr + ex * 8 + 128);
        }
        __syncthreads();  // sync2: tile2 ready; tile1 free for next iter
        f4_t acc0 = {bias2[0], bias2[0], bias2[0], bias2[0]};
        f4_t acc1 = {bias2[1], bias2[1], bias2[1], bias2[1]};
#pragma unroll
        for (int ks = 0; ks < 8; ++ks) {
            bf8_t a = *(const bf8_t*)(&tile2[ks * 512 + perm * 8]);
            acc0 = __builtin_amdgcn_mfma_f32_16x16x32_bf16(a, bfr2[0][ks], acc0, 0, 0, 0);
            acc1 = __builtin_amdgcn_mfma_f32_16x16x32_bf16(a, bfr2[1][ks], acc1, 0, 0, 0);
        }
        unsigned short* outp = a2c + (blk16 + mc) * 2048;
        {
            float v0 = fmaxf(acc0[0], 0.f), v1 = fmaxf(acc0[1], 0.f);
            float v2 = fmaxf(acc0[2], 0.f), v3 = fmaxf(acc0[3], 0.f);
            s0 += v0; q0 += v0 * v0; s0 += v1; q0 += v1 * v1;
            s0 += v2; q0 += v2 * v2; s0 += v3; q0 += v3 * v3;
            u2_t pw; pw[0] = cvt_pk(v0, v1); pw[1] = cvt_pk(v2, v3);
            __builtin_nontemporal_store(pw,
                (u2_t*)(outp + (((w * 2) * 16 + l15) * 4 + quad) * 4));
        }
        {
            float v0 = fmaxf(acc1[0], 0.f), v1 = fmaxf(acc1[1], 0.f);
            float v2 = fmaxf(acc1[2], 0.f), v3 = fmaxf(acc1[3], 0.f);
            s1 += v0; q1 += v0 * v0; s1 += v1; q1 += v1 * v1;
            s1 += v2; q1 += v2 * v2; s1 += v3; q1 += v3 * v3;
            u2_t pw; pw[0] = cvt_pk(v0, v1); pw[1] = cvt_pk(v2, v3);
            __builtin_nontemporal_store(pw,
                (u2_t*)(outp + (((w * 2 + 1) * 16 + l15) * 4 + quad) * 4));
        }
    }
    s0 += __shfl_xor(s0, 16); s0 += __shfl_xor(s0, 32);
    q0 += __shfl_xor(q0, 16); q0 += __shfl_xor(q0, 32);
    s1 += __shfl_xor(s1, 16); s1 += __shfl_xor(s1, 32);
    q1 += __shfl_xor(q1, 16); q1 += __shfl_xor(q1, 32);
    if (lane < 16) {
        float* sl = slots + (size_t)(bid & 63) * 256;
        const int c0 = (w * 2) * 16 + l15;
        atomicAdd(&sl[c0], s0); atomicAdd(&sl[128 + c0], q0);
        atomicAdd(&sl[c0 + 16], s1); atomicAdd(&sl[128 + c0 + 16], q1);
    }
}

__global__ __launch_bounds__(128) void k_fold2(const float* __restrict__ slots,
        const float* __restrict__ g2, const float* __restrict__ b2n,
        const float* __restrict__ W3, const float* __restrict__ b3,
        float* __restrict__ w3p, float* __restrict__ b3p) {
    __shared__ float red[128];
    const int tid = threadIdx.x;
    float S = 0.f, Q = 0.f;
    for (int s = 0; s < 64; ++s) { S += slots[s * 256 + tid]; Q += slots[s * 256 + 128 + tid]; }
    const float invE = 1.f / (float)N_EDGES;
    float mu = S * invE;
    float var = Q * invE - mu * mu;
    float scl = g2[tid] * rsqrtf(var + 1e-5f);
    float shf = b2n[tid] - mu * scl;
    w3p[tid] = W3[tid] * scl;
    red[tid] = W3[tid] * shf;
    __syncthreads();
    for (int st = 64; st > 0; st >>= 1) {
        if (tid < st) red[tid] += red[tid + st];
        __syncthreads();
    }
    if (tid == 0) b3p[0] = b3[0] + red[0];
}

// out = a2 . w3' + b3' from C-layout cells; wave per 16-row block, shuffle reduce.
__global__ __launch_bounds__(256) void k_L3(const unsigned short* __restrict__ a2c,
        const float* __restrict__ w3p, const float* __restrict__ b3p, float* __restrict__ out) {
    __shared__ float wl[128];
    const int tid = threadIdx.x;
    if (tid < 128) wl[tid] = w3p[tid];
    __syncthreads();
    const int w = tid >> 6, lane = tid & 63, q = lane >> 4, c = lane & 15;
    const float bb = b3p[0];
#pragma unroll
    for (int i = 0; i < 4; ++i) {
        const size_t b = (size_t)blockIdx.x * 16 + w * 4 + i;
        const unsigned short* bp = a2c + b * 2048 + c * 16 + q * 4;
        float a0 = 0.f, a1r = 0.f, a2r = 0.f, a3r = 0.f;
#pragma unroll
        for (int jt = 0; jt < 8; ++jt) {
            u2_t v = __builtin_nontemporal_load((const u2_t*)(bp + jt * 256));
            const unsigned short* u = (const unsigned short*)&v;
            const float wv = wl[jt * 16 + c];
            a0 += bf2f(u[0]) * wv; a1r += bf2f(u[1]) * wv;
            a2r += bf2f(u[2]) * wv; a3r += bf2f(u[3]) * wv;
        }
#pragma unroll
        for (int d = 1; d <= 8; d <<= 1) {
            a0 += __shfl_xor(a0, d); a1r += __shfl_xor(a1r, d);
            a2r += __shfl_xor(a2r, d); a3r += __shfl_xor(a3r, d);
        }
        if (c == 0) {
            f4_t o = {a0 + bb, a1r + bb, a2r + bb, a3r + bb};
            *(f4_t*)(out + b * 16 + q * 4) = o;
        }
    }
}

extern "C" void kernel_launch(void* const* d_in, const int* in_sizes, int n_in,
                              void* d_out, int out_size, void* d_ws, size_t ws_size,
                              hipStream_t stream) {
    (void)in_sizes; (void)n_in; (void)out_size; (void)ws_size;
    const float* h   = (const float*)d_in[0];
    const float* e   = (const float*)d_in[1];
    const int*   src = (const int*)d_in[2];
    const int*   dst = (const int*)d_in[3];
    const float* bn0_g = (const float*)d_in[4];
    const float* bn0_b = (const float*)d_in[5];
    const float* W1 = (const float*)d_in[6];
    const float* b1 = (const float*)d_in[7];
    const float* bn1_g = (const float*)d_in[8];
    const float* bn1_b = (const float*)d_in[9];
    const float* W2 = (const float*)d_in[10];
    const float* b2 = (const float*)d_in[11];
    const float* bn2_g = (const float*)d_in[12];
    const float* bn2_b = (const float*)d_in[13];
    const float* W3 = (const float*)d_in[14];
    const float* b3 = (const float*)d_in[15];

    char* ws = (char*)d_ws;
    size_t off = 0;
    auto alloc = [&](size_t bytes) { char* p = ws + off; off += (bytes + 255) & ~(size_t)255; return p; };
    int*   cnt_s = (int*)alloc((size_t)N_NODES * 4);
    int*   cnt_d = (int*)alloc((size_t)N_NODES * 4);
    float* bn0_sum = (float*)alloc(320 * 4);
    float* bn0_sq  = (float*)alloc(320 * 4);
    float* bn1_slots = (float*)alloc(64 * 512 * 4);
    float* bn2_slots = (float*)alloc(64 * 256 * 4);
    const size_t zero_end = off;
    unsigned short* W1s = (unsigned short*)alloc(256 * 128 * 2);
    unsigned short* W1d = (unsigned short*)alloc(256 * 128 * 2);
    unsigned short* W1e = (unsigned short*)alloc(256 * 64 * 2);
    float* b1p = (float*)alloc(256 * 4);
    unsigned short* W2p = (unsigned short*)alloc(128 * 256 * 2);
    float* b2p = (float*)alloc(128 * 4);
    float* w3p = (float*)alloc(128 * 4);
    float* b3p = (float*)alloc(4);
    unsigned short* Ps = (unsigned short*)alloc((size_t)N_NODES * 256 * 2);
    unsigned short* Pd = (unsigned short*)alloc((size_t)N_NODES * 256 * 2);
    unsigned short* ebf = (unsigned short*)alloc((size_t)(N_EDGES / 16) * 2048); // 102.4 MB
    unsigned short* a2c = (unsigned short*)alloc((size_t)(N_EDGES / 16) * 4096); // 204.8 MB

    hipMemsetAsync(d_ws, 0, zero_end, stream);
    k_ecvt<<<1024, 256, 0, stream>>>(e, src, dst, ebf, cnt_s, cnt_d, bn0_sum, bn0_sq);
    k_hstats<<<400, 256, 0, stream>>>(h, cnt_s, cnt_d, bn0_sum, bn0_sq);
    k_foldW1<<<1, 320, 0, stream>>>(bn0_sum, bn0_sq, bn0_g, bn0_b, W1, b1, W1s, W1d, W1e, b1p);
    k_P<<<dim3(196, 2), 256, 0, stream>>>(h, W1s, W1d, Ps, Pd);
    k_stats1<<<N_EDGES / 256, 256, 0, stream>>>(ebf, src, dst, Ps, Pd, W1e, b1p, bn1_slots);
    k_fold1<<<1, 256, 0, stream>>>(bn1_slots, bn1_g, bn1_b, W2, b2, W2p, b2p);
    k_L12<<<1562, 256, 0, stream>>>(ebf, src, dst, Ps, Pd, W1e, b1p, W2p, b2p, a2c, bn2_slots, 0);
    k_L12<<<1563, 256, 0, stream>>>(ebf, src, dst, Ps, Pd, W1e, b1p, W2p, b2p, a2c, bn2_slots, 1562);
    k_fold2<<<1, 128, 0, stream>>>(bn2_slots, bn2_g, bn2_b, W3, b3, w3p, b3p);
    k_L3<<<N_EDGES / 256, 256, 0, stream>>>(a2c, w3p, b3p, (float*)d_out);
}